// Round 10
// baseline (806.168 us; speedup 1.0000x reference)
//
#include <hip/hip_runtime.h>

#define N_NODES 20000
#define N_EDGES 100000
#define CIN     64
#define A_DIM   32
#define CCH     256
#define NBOX    128
#define FD      1024
#define HID     1024
#define OUT_STRIDE 2048

typedef __attribute__((ext_vector_type(8))) short          short8;
typedef __attribute__((ext_vector_type(8))) unsigned short ushort8;
typedef __attribute__((ext_vector_type(4))) unsigned short ushort4v;
typedef __attribute__((ext_vector_type(4))) float          floatx4;

__device__ __forceinline__ unsigned short f2bf(float f) {
    unsigned int u = __float_as_uint(f);
    u += 0x7fff + ((u >> 16) & 1);
    return (unsigned short)(u >> 16);
}
__device__ __forceinline__ float bf2f(unsigned short h) {
    return __uint_as_float(((unsigned int)h) << 16);
}

// async global->LDS, 16B per lane; LDS dest is wave-uniform base + lane*16
__device__ __forceinline__ void glds16(const unsigned short* g, unsigned short* l) {
    __builtin_amdgcn_global_load_lds(
        (const __attribute__((address_space(1))) unsigned int*)g,
        (__attribute__((address_space(3))) unsigned int*)l,
        16, 0, 0);
}

// ---------------------------------------------------------------------------
// GEMM descriptor (dual-dispatch support: one launch can carry two GEMMs).
// 128x128 tile, BK=64 (halves barrier/drain count per K-col vs BK=32 -- the
// 2-phase structure's dominant cost). acc stays 4x4 = 64 VGPR (the 128x256
// tile's 128-reg acc spilled to AGPR -> 1 wave/SIMD -> 2x regression; do not
// regrow the tile). LDS rows are 128B, so fragment reads use a chunk-XOR
// swizzle (chunk ^= row&7) applied BOTH at the global source address and at
// the ds_read address (glds dest must stay linear -- rule #21).
// All K must be multiples of 64 (R-GEMM inputs are zero-padded 32->64).
// ---------------------------------------------------------------------------
struct GD {
    const unsigned short* src0b;
    const unsigned short* src1b;
    const unsigned short* Wt;
    const float* bias;
    const int* ridx0;
    float* outf;
    unsigned short* outb;
    int s0, o0, C0, s1, o1, do_relu, sof, oof, sob, oob, rmode, M, K, nbc;
};

__global__ __launch_bounds__(256) void mfma_dense(GD A, GD B, int n0)
{
    __shared__ __align__(16) unsigned short SM[2][8192];   // As=SM[0], Bs=SM[1]

    const int tid = threadIdx.x;
    const bool fa = (int)blockIdx.x < n0;

    const unsigned short* src0b = fa ? A.src0b : B.src0b;
    const unsigned short* src1b = fa ? A.src1b : B.src1b;
    const unsigned short* Wt    = fa ? A.Wt    : B.Wt;
    const float* bias           = fa ? A.bias  : B.bias;
    const int*   ridx0          = fa ? A.ridx0 : B.ridx0;
    float* outf                 = fa ? A.outf  : B.outf;
    unsigned short* outb        = fa ? A.outb  : B.outb;
    const int s0  = fa ? A.s0  : B.s0,  o0  = fa ? A.o0  : B.o0;
    const int C0  = fa ? A.C0  : B.C0;
    const int s1  = fa ? A.s1  : B.s1,  o1  = fa ? A.o1  : B.o1;
    const int do_relu = fa ? A.do_relu : B.do_relu;
    const int sof = fa ? A.sof : B.sof, oof = fa ? A.oof : B.oof;
    const int sob = fa ? A.sob : B.sob, oob = fa ? A.oob : B.oob;
    const int rmode = fa ? A.rmode : B.rmode;
    const int M   = fa ? A.M   : B.M;
    const int K   = fa ? A.K   : B.K;
    const int nbc = fa ? A.nbc : B.nbc;

    // bijective XCD swizzle within this descriptor's sub-grid
    const int nwg = fa ? n0 : (int)gridDim.x - n0;
    const int lb  = (int)blockIdx.x - (fa ? 0 : n0);
    const int q8  = nwg >> 3, r8 = nwg & 7;
    const int xcd = lb & 7, boff = lb >> 3;
    const int bid = (xcd < r8 ? xcd * (q8 + 1)
                              : r8 * (q8 + 1) + (xcd - r8) * q8) + boff;

    const int rb   = bid / nbc, cb = bid % nbc;
    const int r0   = rb * 128, c0 = cb * 128;
    const int wave = tid >> 6, lane = tid & 63;
    const int quad = lane >> 4, l16 = lane & 15;
    const int wm   = (wave & 1) * 64, wn = (wave >> 1) * 64;

    // staging slot geometry (BK=64, [128][64] bf16 tiles, 128B rows):
    // slot g = i*256 + tid covers LDS bytes [g*16, g*16+16); row = g>>3,
    // linear chunk = g&7. Source chunk is XOR-swizzled: kchS = (chunk^row&7)*8
    // so that LDS(row, c) holds global chunk c^(row&7).
    const int rr8  = tid >> 3;                          // row within 32-row group
    const int kchS = (((tid & 7) ^ (rr8 & 7)) << 3);    // swizzled src k-chunk
    int arowv[4], growv[4];
    #pragma unroll
    for (int i = 0; i < 4; ++i) {
        int gr2 = r0 + i * 32 + rr8;
        if (gr2 >= M) gr2 = M - 1;
        growv[i] = gr2;
        arowv[i] = ridx0 ? ridx0[gr2] : gr2;
    }
    unsigned short* AsW = &SM[0][wave * 512];   // +i*2048 shorts per slot group
    unsigned short* BsW = &SM[1][wave * 512];

    floatx4 acc[4][4];
    #pragma unroll
    for (int i = 0; i < 4; ++i)
        #pragma unroll
        for (int j = 0; j < 4; ++j) acc[i][j] = (floatx4){0.f, 0.f, 0.f, 0.f};

    for (int k0 = 0; k0 < K; k0 += 64) {
        const int kk = k0 + kchS;
        #pragma unroll
        for (int i = 0; i < 4; ++i) {
            const unsigned short* ga = (kk < C0)
                ? src0b + (long)arowv[i] * s0 + o0 + kk
                : src1b + (long)growv[i] * s1 + o1 + (kk - C0);
            glds16(ga, AsW + i * 2048);
            glds16(Wt + (long)(c0 + i * 32 + rr8) * K + kk, BsW + i * 2048);
        }
        __syncthreads();

        #pragma unroll
        for (int ks = 0; ks < 2; ++ks) {
            short8 af[4], bfr[4];
            #pragma unroll
            for (int mt = 0; mt < 4; ++mt) {
                const int r = wm + mt * 16 + l16;
                af[mt] = *(const short8*)(
                    &SM[0][r * 64 + ((((ks << 2) | quad) ^ (r & 7)) << 3)]);
            }
            #pragma unroll
            for (int nt = 0; nt < 4; ++nt) {
                const int r = wn + nt * 16 + l16;
                bfr[nt] = *(const short8*)(
                    &SM[1][r * 64 + ((((ks << 2) | quad) ^ (r & 7)) << 3)]);
            }
            #pragma unroll
            for (int mt = 0; mt < 4; ++mt)
                #pragma unroll
                for (int nt = 0; nt < 4; ++nt)
                    acc[mt][nt] = __builtin_amdgcn_mfma_f32_16x16x32_bf16(
                        af[mt], bfr[nt], acc[mt][nt], 0, 0, 0);
        }
        __syncthreads();
    }

    if (outf) {
        #pragma unroll
        for (int nt = 0; nt < 4; ++nt) {
            const int gc = c0 + wn + nt * 16 + l16;
            const float bv = bias ? bias[gc] : 0.f;
            #pragma unroll
            for (int mt = 0; mt < 4; ++mt) {
                #pragma unroll
                for (int reg = 0; reg < 4; ++reg) {
                    const int grr = r0 + wm + mt * 16 + quad * 4 + reg;
                    if (grr < M) {
                        float v = acc[mt][nt][reg] + bv;
                        if (do_relu) v = fmaxf(v, 0.f);
                        outf[(long)grr * sof + oof + gc] = v;
                    }
                }
            }
        }
    }
    if (outb) {
        // bf16 path: LDS-staged coalesced epilogue, 2 passes of 64 rows.
        unsigned short* Cs = &SM[0][0];        // 64*128 shorts = fits in As
        #pragma unroll
        for (int p = 0; p < 2; ++p) {
            if (wm == p * 64) {
                #pragma unroll
                for (int nt = 0; nt < 4; ++nt) {
                    const int col = wn + nt * 16 + l16;
                    const float bv = bias ? bias[c0 + col] : 0.f;
                    #pragma unroll
                    for (int mt = 0; mt < 4; ++mt) {
                        #pragma unroll
                        for (int reg = 0; reg < 4; ++reg) {
                            float v = acc[mt][nt][reg] + bv;
                            if (do_relu) v = fmaxf(v, 0.f);
                            Cs[(mt * 16 + quad * 4 + reg) * 128 + col] = f2bf(v);
                        }
                    }
                }
            }
            __syncthreads();
            const int rl  = tid >> 2;
            const int cc0 = (tid & 3) << 3;
            const int grr2 = r0 + p * 64 + rl;
            if (grr2 < M) {
                const long rowbase = (rmode == 2)
                    ? ((long)(c0 >> 8) * ((long)N_EDGES * 256)
                       + (long)grr2 * 256 + (c0 & 255))
                    : ((long)grr2 * sob + oob + c0);
                #pragma unroll
                for (int j = 0; j < 4; ++j)
                    *(ushort8*)(outb + rowbase + cc0 + j * 32) =
                        *(const ushort8*)(&Cs[rl * 128 + cc0 + j * 32]);
            }
            __syncthreads();
        }
    }
}

// ---------------------------------------------------------------------------
// Aggregation: one wave per dst node, TWO edges in flight (named slots A/B).
// Summation order identical to serial loop -> bitwise-identical results.
// ---------------------------------------------------------------------------
__global__ __launch_bounds__(256) void agg_kernel(
    const unsigned short* __restrict__ pq,
    const int* __restrict__ rowptr,
    const int* __restrict__ ssrc,
    const float* __restrict__ sew,
    const unsigned short* __restrict__ Rb,
    const float* __restrict__ resid,
    const float* __restrict__ bias,
    float* __restrict__ out, int fofs, int rofs,
    unsigned short* __restrict__ nfbf, int nofs)
{
    const int wid  = (blockIdx.x * blockDim.x + threadIdx.x) >> 6;
    const int lane = threadIdx.x & 63;
    if (wid >= N_NODES) return;
    const int c = lane * 4;

    const ushort4v p4 = *(const ushort4v*)(pq + (long)wid * 512 + c);
    const float4 bb = *(const float4*)(bias + c);
    float pb[4] = {bf2f(p4[0]) + bb.x, bf2f(p4[1]) + bb.y,
                   bf2f(p4[2]) + bb.z, bf2f(p4[3]) + bb.w};
    float acc[4] = {0.f, 0.f, 0.f, 0.f};

    int s = rowptr[wid];
    const int sEnd = rowptr[wid + 1];

    ushort4v qA, rA, qB, rB;
    float wA = 0.f, wB = 0.f;
    if (s < sEnd) {
        const int n_ = ssrc[s];
        wA = sew[s];
        qA = *(const ushort4v*)(pq + (long)n_ * 512 + 256 + c);
        rA = *(const ushort4v*)(Rb + (long)s * 256 + c);
    }
    if (s + 1 < sEnd) {
        const int n_ = ssrc[s + 1];
        wB = sew[s + 1];
        qB = *(const ushort4v*)(pq + (long)n_ * 512 + 256 + c);
        rB = *(const ushort4v*)(Rb + (long)(s + 1) * 256 + c);
    }
    while (s + 1 < sEnd) {
        #pragma unroll
        for (int j = 0; j < 4; ++j)
            acc[j] += fmaxf(pb[j] + bf2f(qA[j]) + bf2f(rA[j]), 0.f) * wA;
        if (s + 2 < sEnd) {
            const int n_ = ssrc[s + 2];
            wA = sew[s + 2];
            qA = *(const ushort4v*)(pq + (long)n_ * 512 + 256 + c);
            rA = *(const ushort4v*)(Rb + (long)(s + 2) * 256 + c);
        }
        #pragma unroll
        for (int j = 0; j < 4; ++j)
            acc[j] += fmaxf(pb[j] + bf2f(qB[j]) + bf2f(rB[j]), 0.f) * wB;
        if (s + 3 < sEnd) {
            const int n_ = ssrc[s + 3];
            wB = sew[s + 3];
            qB = *(const ushort4v*)(pq + (long)n_ * 512 + 256 + c);
            rB = *(const ushort4v*)(Rb + (long)(s + 3) * 256 + c);
        }
        s += 2;
    }
    if (s < sEnd) {
        #pragma unroll
        for (int j = 0; j < 4; ++j)
            acc[j] += fmaxf(pb[j] + bf2f(qA[j]) + bf2f(rA[j]), 0.f) * wA;
    }
    if (rofs >= 0) {
        const float4 f4 = *(const float4*)(resid + (long)wid * OUT_STRIDE + rofs + c);
        acc[0] += f4.x; acc[1] += f4.y; acc[2] += f4.z; acc[3] += f4.w;
    }
    float4 o; o.x = acc[0]; o.y = acc[1]; o.z = acc[2]; o.w = acc[3];
    *(float4*)(out + (long)wid * OUT_STRIDE + fofs + c) = o;
    ushort4v hb = (ushort4v){f2bf(acc[0]), f2bf(acc[1]), f2bf(acc[2]), f2bf(acc[3])};
    *(ushort4v*)(nfbf + (long)wid * FD + nofs + c) = hb;
}

// ---------------------------------------------------------------------------
// Mega prep kernel: both f32->bf16 converts + all weight preps in ONE launch.
// eab is zero-padded to [E][64]; wtr to [1024][64] (R-GEMM K=64).
// ---------------------------------------------------------------------------
__device__ __forceinline__ void tr_block(const float* inp, unsigned short* outp,
                                         int K, int N, int bidx, int tid,
                                         float (*tile)[33])
{
    const int nbx = N >> 5;
    const int n0 = (bidx % nbx) << 5;
    const int k0 = (bidx / nbx) << 5;
    const int tx = tid & 31, ty = tid >> 5;
    #pragma unroll
    for (int r = 0; r < 4; ++r)
        tile[ty + r * 8][tx] = inp[(long)(k0 + ty + r * 8) * N + n0 + tx];
    __syncthreads();
    #pragma unroll
    for (int r = 0; r < 4; ++r)
        outp[(long)(n0 + ty + r * 8) * K + k0 + tx] = f2bf(tile[tx][ty + r * 8]);
}

#define PB_CVTX  1250   // 20000*64/4/256
#define PB_CVTE  3125   // 100000*64/8/256 (padded eab, ushort8 per thread)
#define PB_WPQ0  128
#define PB_WPQ3  384
#define PB_WTR   256    // 4 slabs * (256*64/256)
#define PB_TS0   80
#define PB_TS3   384
#define PB_TF    1024
#define PREP_BLOCKS (PB_CVTX+PB_CVTE+PB_WPQ0+PB_WPQ3+PB_WTR+PB_TS0+PB_TS3+PB_TF+PB_TF)

__global__ __launch_bounds__(256) void prep_all(
    const float* __restrict__ x, const float* __restrict__ ea,
    const float* __restrict__ W_msg0, const float* __restrict__ W_msg,
    const float* __restrict__ W_sup0, const float* __restrict__ W_sup,
    const float* __restrict__ W_fuse, const float* __restrict__ W_fsup,
    unsigned short* __restrict__ xb, unsigned short* __restrict__ eab,
    unsigned short* __restrict__ wpq0, unsigned short* __restrict__ wpq,
    unsigned short* __restrict__ wtr,
    unsigned short* __restrict__ wt_sup0, unsigned short* __restrict__ wt_sup,
    unsigned short* __restrict__ wt_fuse, unsigned short* __restrict__ wt_fsup)
{
    __shared__ float tile[32][33];
    const int tid = threadIdx.x;
    int b = blockIdx.x;

    if (b < PB_CVTX) {
        int i = b * 256 + tid;
        float4 v = ((const float4*)x)[i];
        ((ushort4v*)xb)[i] = (ushort4v){f2bf(v.x), f2bf(v.y), f2bf(v.z), f2bf(v.w)};
        return;
    }
    b -= PB_CVTX;
    if (b < PB_CVTE) {           // ea -> eab [E][64], cols 32..63 zero
        int idx = b * 256 + tid;               // ushort8 index
        int e = idx >> 3, col0 = (idx & 7) << 3;
        ushort8 h;
        if (col0 < 32) {
            const float4* p = (const float4*)(ea + (long)e * 32 + col0);
            float4 a = p[0], q = p[1];
            h = (ushort8){f2bf(a.x), f2bf(a.y), f2bf(a.z), f2bf(a.w),
                          f2bf(q.x), f2bf(q.y), f2bf(q.z), f2bf(q.w)};
        } else {
            h = (ushort8){0,0,0,0,0,0,0,0};
        }
        *(ushort8*)(eab + (long)idx * 8) = h;
        return;
    }
    b -= PB_CVTE;
    if (b < PB_WPQ0) {
        int i = b * 256 + tid;
        int nn = i >> 6, k = i & 63;
        float v = (nn < 256) ? (W_msg0[k * 256 + nn] - W_msg0[(64 + k) * 256 + nn])
                             : (W_msg0[(64 + k) * 256 + (nn - 256)]);
        wpq0[(long)nn * 64 + k] = f2bf(v);
        return;
    }
    b -= PB_WPQ0;
    if (b < PB_WPQ3) {
        const int slab = b / 128, bb = b % 128;
        const float* Wi = W_msg + (long)slab * 544 * 256;
        unsigned short* Wo = wpq + (long)slab * 512 * 256;
        const int n0 = (bb & 15) << 5;
        const int k0 = (bb >> 4) << 5;
        const int tx = tid & 31, ty = tid >> 5;
        #pragma unroll
        for (int r = 0; r < 4; ++r) {
            const int k = k0 + ty + r * 8;
            float v;
            if (n0 < 256)
                v = Wi[(long)k * 256 + n0 + tx] - Wi[(long)(256 + k) * 256 + n0 + tx];
            else
                v = Wi[(long)(256 + k) * 256 + (n0 - 256) + tx];
            tile[ty + r * 8][tx] = v;
        }
        __syncthreads();
        #pragma unroll
        for (int r = 0; r < 4; ++r)
            Wo[(long)(n0 + ty + r * 8) * 256 + k0 + tx] = f2bf(tile[tx][ty + r * 8]);
        return;
    }
    b -= PB_WPQ3;
    if (b < PB_WTR) {            // wtr [1024][64] layer-major, cols 32..63 zero
        const int j = b >> 6;
        const float* Wi = (j == 0) ? (W_msg0 + 2 * CIN * 256)
                                   : (W_msg + (long)(j - 1) * 544 * 256 + 2 * CCH * 256);
        unsigned short* Wo = wtr + (long)j * 256 * 64;
        int i = (b & 63) * 256 + tid;          // < 16384
        int n = i >> 6, k = i & 63;
        Wo[(long)n * 64 + k] = (k < 32) ? f2bf(Wi[(long)k * 256 + n])
                                        : (unsigned short)0;
        return;
    }
    b -= PB_WTR;
    if (b < PB_TS0) { tr_block(W_sup0, wt_sup0, 320, 256, b, tid, tile); return; }
    b -= PB_TS0;
    if (b < PB_TS3) {
        const int slab = b / 128;
        tr_block(W_sup + (long)slab * 512 * 256, wt_sup + (long)slab * 256 * 512,
                 512, 256, b % 128, tid, tile);
        return;
    }
    b -= PB_TS3;
    if (b < PB_TF) { tr_block(W_fuse, wt_fuse, 1024, 1024, b, tid, tile); return; }
    b -= PB_TF;
    tr_block(W_fsup, wt_fsup, 1024, 1024, b, tid, tile);
}

// ---------------------------------------------------------------------------
// CSR build (edge + box variants merged per stage)
// ---------------------------------------------------------------------------
__global__ void zero2(int* __restrict__ cnt, int* __restrict__ bcnt) {
    int i = blockIdx.x * blockDim.x + threadIdx.x;
    if (i < N_NODES + 1) cnt[i] = 0;
    else if (i - (N_NODES + 1) < 129) bcnt[i - (N_NODES + 1)] = 0;
}
__global__ void hist2(const int* __restrict__ dst, const int* __restrict__ bbox,
                      int* __restrict__ cnt, int* __restrict__ bcnt) {
    int i = blockIdx.x * blockDim.x + threadIdx.x;
    if (i < N_EDGES) atomicAdd(&cnt[dst[i]], 1);
    else if (i - N_EDGES < N_NODES) atomicAdd(&bcnt[bbox[i - N_EDGES]], 1);
}
__global__ __launch_bounds__(1024) void scan2(
    const int* __restrict__ cnt,  int* __restrict__ rowptr, int* __restrict__ ofs,
    const int* __restrict__ bcnt, int* __restrict__ bptr,   int* __restrict__ bofs)
{
    __shared__ int part[1024];
    const int tid = threadIdx.x;
    const int n = blockIdx.x == 0 ? N_NODES : NBOX;
    const int* c   = blockIdx.x == 0 ? cnt    : bcnt;
    int* rp        = blockIdx.x == 0 ? rowptr : bptr;
    int* op        = blockIdx.x == 0 ? ofs    : bofs;
    const int chunk = (n + 1023) >> 10;
    int s = 0;
    for (int j = 0; j < chunk; ++j) {
        int i = tid * chunk + j;
        if (i < n) s += c[i];
    }
    part[tid] = s; __syncthreads();
    for (int d = 1; d < 1024; d <<= 1) {
        int v = (tid >= d) ? part[tid - d] : 0;
        __syncthreads();
        part[tid] += v;
        __syncthreads();
    }
    int run = (tid > 0) ? part[tid - 1] : 0;
    for (int j = 0; j < chunk; ++j) {
        int i = tid * chunk + j;
        if (i < n) { rp[i] = run; op[i] = run; run += c[i]; }
    }
    if (tid == 1023) rp[n] = part[1023];
}
__global__ void scatter2(const int* __restrict__ src, const int* __restrict__ dst,
                         const float* __restrict__ ew, int* __restrict__ ofs,
                         int* __restrict__ ssrc, float* __restrict__ sew,
                         int* __restrict__ seid,
                         const int* __restrict__ bbox, int* __restrict__ bofs,
                         int* __restrict__ snode) {
    int i = blockIdx.x * blockDim.x + threadIdx.x;
    if (i < N_EDGES) {
        int pos = atomicAdd(&ofs[dst[i]], 1);
        ssrc[pos] = src[i];
        sew[pos]  = ew[i];
        seid[pos] = i;
    } else if (i - N_EDGES < N_NODES) {
        int j = i - N_EDGES;
        int pos = atomicAdd(&bofs[bbox[j]], 1);
        snode[pos] = j;
    }
}

// ---------------------------------------------------------------------------
// Box mean via CSR, 1-deep gather prefetch. Emits fp32 + bf16 fsmean.
// ---------------------------------------------------------------------------
__global__ __launch_bounds__(256) void box_mean_csr(
    const unsigned short* __restrict__ fsbf, const int* __restrict__ bptr,
    const int* __restrict__ snode, float* __restrict__ out_super,
    unsigned short* __restrict__ fsmeanb)
{
    const int b = blockIdx.x >> 2;
    const int c = ((blockIdx.x & 3) << 8) + threadIdx.x;
    const int s0 = bptr[b], s1 = bptr[b + 1];
    float sum = 0.f;
    int s = s0;
    unsigned short hn = 0;
    if (s < s1) hn = fsbf[(long)snode[s] * FD + c];
    while (s < s1) {
        const unsigned short h = hn;
        if (s + 1 < s1) hn = fsbf[(long)snode[s + 1] * FD + c];
        sum += bf2f(h);
        ++s;
    }
    const float mean = sum / fmaxf((float)(s1 - s0), 1.f);
    out_super[(long)b * OUT_STRIDE + HID + c] = mean;
    fsmeanb[(long)b * FD + c] = f2bf(mean);
}

// ---------------------------------------------------------------------------
extern "C" void kernel_launch(void* const* d_in, const int* in_sizes, int n_in,
                              void* d_out, int out_size, void* d_ws, size_t ws_size,
                              hipStream_t stream) {
    const float* x      = (const float*)d_in[0];
    const int*   edges  = (const int*)d_in[1];
    const float* ew     = (const float*)d_in[2];
    const float* ea     = (const float*)d_in[3];
    const int*   bbox   = (const int*)d_in[4];
    const float* W_msg0 = (const float*)d_in[6];
    const float* b_msg0 = (const float*)d_in[7];
    const float* W_sup0 = (const float*)d_in[8];
    const float* b_sup0 = (const float*)d_in[9];
    const float* W_msg  = (const float*)d_in[10];
    const float* b_msg  = (const float*)d_in[11];
    const float* W_sup  = (const float*)d_in[12];
    const float* b_sup  = (const float*)d_in[13];
    const float* W_fuse = (const float*)d_in[14];
    const float* b_fuse = (const float*)d_in[15];
    const float* W_fsup = (const float*)d_in[16];
    const float* b_fsup = (const float*)d_in[17];

    float* out       = (float*)d_out;
    float* out_super = out + (long)N_NODES * OUT_STRIDE;

    // ---- workspace layout ----
    char* w = (char*)d_ws;
    auto alloc = [&](size_t bytes) { char* p = w; w += (bytes + 63) & ~63ULL; return p; };
    unsigned short* fsbf    = (unsigned short*)alloc((size_t)N_NODES * FD * 2);
    unsigned short* nfbf    = (unsigned short*)alloc((size_t)N_NODES * FD * 2);
    unsigned short* pq      = (unsigned short*)alloc((size_t)N_NODES * 512 * 2);
    unsigned short* xb      = (unsigned short*)alloc((size_t)N_NODES * CIN * 2);
    unsigned short* eab     = (unsigned short*)alloc((size_t)N_EDGES * 64 * 2);
    unsigned short* Rb4     = (unsigned short*)alloc((size_t)N_EDGES * 1024 * 2);
    unsigned short* wpq0    = (unsigned short*)alloc((size_t)512 * CIN * 2);
    unsigned short* wpq     = (unsigned short*)alloc((size_t)3 * 512 * CCH * 2);
    unsigned short* wtr     = (unsigned short*)alloc((size_t)4 * 256 * 64 * 2);
    unsigned short* wt_sup0 = (unsigned short*)alloc((size_t)256 * 320 * 2);
    unsigned short* wt_sup  = (unsigned short*)alloc((size_t)3 * 256 * 512 * 2);
    unsigned short* wt_fuse = (unsigned short*)alloc((size_t)1024 * 1024 * 2);
    unsigned short* wt_fsup = (unsigned short*)alloc((size_t)1024 * 1024 * 2);
    unsigned short* fsmeanb = (unsigned short*)alloc((size_t)NBOX * FD * 2);
    float* sew        = (float*)alloc((size_t)N_EDGES * 4);
    int* cnt          = (int*)alloc((size_t)(N_NODES + 1) * 4);
    int* rowptr       = (int*)alloc((size_t)(N_NODES + 1) * 4);
    int* ofs          = (int*)alloc((size_t)(N_NODES + 1) * 4);
    int* ssrc         = (int*)alloc((size_t)N_EDGES * 4);
    int* seid         = (int*)alloc((size_t)N_EDGES * 4);
    int* bcnt         = (int*)alloc(129 * 4);
    int* bptr         = (int*)alloc(129 * 4);
    int* bofs         = (int*)alloc(129 * 4);
    int* snode        = (int*)alloc((size_t)N_NODES * 4);

    const int* srcp = edges;
    const int* dstp = edges + N_EDGES;

    // ---- prep (1 launch) ----
    prep_all<<<PREP_BLOCKS, 256, 0, stream>>>(
        x, ea, W_msg0, W_msg, W_sup0, W_sup, W_fuse, W_fsup,
        xb, eab, wpq0, wpq, wtr, wt_sup0, wt_sup, wt_fuse, wt_fsup);

    // ---- CSR build (4 launches) ----
    zero2<<<(N_NODES + 130 + 255) / 256, 256, 0, stream>>>(cnt, bcnt);
    hist2<<<(N_EDGES + N_NODES + 255) / 256, 256, 0, stream>>>(dstp, bbox, cnt, bcnt);
    scan2<<<2, 1024, 0, stream>>>(cnt, rowptr, ofs, bcnt, bptr, bofs);
    scatter2<<<(N_EDGES + N_NODES + 255) / 256, 256, 0, stream>>>(
        srcp, dstp, ew, ofs, ssrc, sew, seid, bbox, bofs, snode);

    const int GRB = (N_NODES + 127) / 128;   // 157
    const int GEB = (N_EDGES + 127) / 128;   // 782
    const long RLS = (long)N_EDGES * 256;    // R layer stride (shorts)

    auto mk = [](const unsigned short* src0b, int s0, int o0, int C0,
                 const int* ridx0,
                 const unsigned short* src1b, int s1, int o1,
                 const unsigned short* Wt, const float* bias, int relu,
                 float* outf, int sof, int oof,
                 unsigned short* outb, int sob, int oob, int rmode,
                 int M, int K, int nbc) {
        GD g;
        g.src0b = src0b; g.s0 = s0; g.o0 = o0; g.C0 = C0;
        g.ridx0 = ridx0;
        g.src1b = src1b; g.s1 = s1; g.o1 = o1;
        g.Wt = Wt; g.bias = bias; g.do_relu = relu;
        g.outf = outf; g.sof = sof; g.oof = oof;
        g.outb = outb; g.sob = sob; g.oob = oob; g.rmode = rmode;
        g.M = M; g.K = K; g.nbc = nbc;
        return g;
    };

    GD gR   = mk(eab, 64, 0, 64, seid, nullptr, 0, 0, wtr, nullptr, 0,
                 nullptr, 0, 0, Rb4, 0, 0, 2, N_EDGES, 64, 8);
    GD gPQh = mk(xb, CIN, 0, CIN, nullptr, nullptr, 0, 0, wpq0, nullptr, 0,
                 nullptr, 0, 0, pq, 512, 0, 0, N_NODES, CIN, 4);
    GD gS0  = mk(nfbf, FD, 0, CCH, nullptr, xb, CIN, 0, wt_sup0, b_sup0, 1,
                 nullptr, 0, 0, fsbf, FD, 0, 0, N_NODES, CCH + CIN, 2);
    GD gPQ[3], gS[3];
    for (int i = 0; i < 3; ++i) {
        gPQ[i] = mk(nfbf, FD, CCH * i, CCH, nullptr, nullptr, 0, 0,
                    wpq + (long)i * 512 * CCH, nullptr, 0,
                    nullptr, 0, 0, pq, 512, 0, 0, N_NODES, CCH, 4);
        gS[i]  = mk(nfbf, FD, CCH * (i + 1), CCH, nullptr, fsbf, FD, CCH * i,
                    wt_sup + (long)i * 256 * 512, b_sup + i * CCH, 1,
                    nullptr, 0, 0, fsbf, FD, CCH * (i + 1), 0, N_NODES, 2 * CCH, 2);
    }
    GD gFU  = mk(nfbf, FD, 0, FD, nullptr, nullptr, 0, 0, wt_fuse, b_fuse, 1,
                 out, OUT_STRIDE, 0, nullptr, 0, 0, 0, N_NODES, FD, 8);
    GD gFS  = mk(fsmeanb, FD, 0, FD, nullptr, nullptr, 0, 0, wt_fsup, b_fsup, 1,
                 out_super, OUT_STRIDE, 0, nullptr, 0, 0, 0, NBOX, FD, 8);

    const int AGRID = (N_NODES + 3) / 4;

    // ---- R GEMM (all 4 layers) || head pq GEMM ----
    mfma_dense<<<GEB * 8 + GRB * 4, 256, 0, stream>>>(gR, gPQh, GEB * 8);

    // ---- head agg ----
    agg_kernel<<<AGRID, 256, 0, stream>>>(pq, rowptr, ssrc, sew,
        Rb4, out, b_msg0, out, HID, -1, nfbf, 0);

    // ---- [sup_head || pq_res0] -> agg_res0 -> [sup_res0 || pq_res1] -> ... ----
    mfma_dense<<<GRB * 6, 256, 0, stream>>>(gS0, gPQ[0], GRB * 2);
    for (int i = 0; i < 3; ++i) {
        agg_kernel<<<AGRID, 256, 0, stream>>>(pq, rowptr, ssrc, sew,
            Rb4 + (long)(i + 1) * RLS, out, b_msg + i * CCH,
            out, HID + CCH * (i + 1), HID + CCH * i, nfbf, CCH * (i + 1));
        if (i < 2)
            mfma_dense<<<GRB * 6, 256, 0, stream>>>(gS[i], gPQ[i + 1], GRB * 2);
    }

    // ---- [sup_res2 || fusion] ----
    mfma_dense<<<GRB * 10, 256, 0, stream>>>(gS[2], gFU, GRB * 2);

    // ---- super path ----
    box_mean_csr<<<NBOX * 4, 256, 0, stream>>>(fsbf, bptr, snode, out_super, fsmeanb);
    mfma_dense<<<8, 256, 0, stream>>>(gFS, gFS, 8);
}

// Round 11
// 782.008 us; speedup vs baseline: 1.0309x; 1.0309x over previous
//
#include <hip/hip_runtime.h>

#define N_NODES 20000
#define N_EDGES 100000
#define CIN     64
#define A_DIM   32
#define CCH     256
#define NBOX    128
#define FD      1024
#define HID     1024
#define OUT_STRIDE 2048

typedef __attribute__((ext_vector_type(8))) short          short8;
typedef __attribute__((ext_vector_type(8))) unsigned short ushort8;
typedef __attribute__((ext_vector_type(4))) unsigned short ushort4v;
typedef __attribute__((ext_vector_type(4))) float          floatx4;

__device__ __forceinline__ unsigned short f2bf(float f) {
    unsigned int u = __float_as_uint(f);
    u += 0x7fff + ((u >> 16) & 1);
    return (unsigned short)(u >> 16);
}
__device__ __forceinline__ float bf2f(unsigned short h) {
    return __uint_as_float(((unsigned int)h) << 16);
}

// async global->LDS, 16B per lane; LDS dest is wave-uniform base + lane*16
__device__ __forceinline__ void glds16(const unsigned short* g, unsigned short* l) {
    __builtin_amdgcn_global_load_lds(
        (const __attribute__((address_space(1))) unsigned int*)g,
        (__attribute__((address_space(3))) unsigned int*)l,
        16, 0, 0);
}

// ---------------------------------------------------------------------------
// GEMM descriptor (dual-dispatch support: one launch can carry two GEMMs).
// 128x128 tile, BK=32, single-buffer staging (measured-best structure).
// Measured dead ends -- do not revisit: 128x256 tile (acc->AGPR, 1 wave/SIMD,
// 2x regression, r8); BK=64+swizzle (conflicts fixed 21x but occupancy drop,
// net -3%, r10); explicit dbuf (neutral, r5).
// K-loop address math is hoisted: per-lane pointers advance += 32/step, and
// the seg0/seg1 select is lifted out of the loop (C0 is always 32-aligned).
// ---------------------------------------------------------------------------
struct GD {
    const unsigned short* src0b;
    const unsigned short* src1b;
    const unsigned short* Wt;
    const float* bias;
    const int* ridx0;
    float* outf;
    unsigned short* outb;
    int s0, o0, C0, s1, o1, do_relu, sof, oof, sob, oob, rmode, M, K, nbc;
};

__global__ __launch_bounds__(256) void mfma_dense(GD A, GD B, int n0)
{
    __shared__ __align__(16) unsigned short SM[2][4096];   // As=SM[0], Bs=SM[1]

    const int tid = threadIdx.x;
    const bool fa = (int)blockIdx.x < n0;

    const unsigned short* src0b = fa ? A.src0b : B.src0b;
    const unsigned short* src1b = fa ? A.src1b : B.src1b;
    const unsigned short* Wt    = fa ? A.Wt    : B.Wt;
    const float* bias           = fa ? A.bias  : B.bias;
    const int*   ridx0          = fa ? A.ridx0 : B.ridx0;
    float* outf                 = fa ? A.outf  : B.outf;
    unsigned short* outb        = fa ? A.outb  : B.outb;
    const int s0  = fa ? A.s0  : B.s0,  o0  = fa ? A.o0  : B.o0;
    const int C0  = fa ? A.C0  : B.C0;
    const int s1  = fa ? A.s1  : B.s1,  o1  = fa ? A.o1  : B.o1;
    const int do_relu = fa ? A.do_relu : B.do_relu;
    const int sof = fa ? A.sof : B.sof, oof = fa ? A.oof : B.oof;
    const int sob = fa ? A.sob : B.sob, oob = fa ? A.oob : B.oob;
    const int rmode = fa ? A.rmode : B.rmode;
    const int M   = fa ? A.M   : B.M;
    const int K   = fa ? A.K   : B.K;
    const int nbc = fa ? A.nbc : B.nbc;

    // bijective XCD swizzle within this descriptor's sub-grid
    const int nwg = fa ? n0 : (int)gridDim.x - n0;
    const int lb  = (int)blockIdx.x - (fa ? 0 : n0);
    const int q8  = nwg >> 3, r8 = nwg & 7;
    const int xcd = lb & 7, boff = lb >> 3;
    const int bid = (xcd < r8 ? xcd * (q8 + 1)
                              : r8 * (q8 + 1) + (xcd - r8) * q8) + boff;

    const int rb   = bid / nbc, cb = bid % nbc;
    const int r0   = rb * 128, c0 = cb * 128;
    const int wave = tid >> 6, lane = tid & 63;
    const int quad = lane >> 4, l16 = lane & 15;
    const int wm   = (wave & 1) * 64, wn = (wave >> 1) * 64;

    // staging slot geometry: slot g = i*256 + tid covers LDS bytes [g*16, g*16+16)
    // row = g>>2 (64B rows), k-chunk = (g&3)*8 bf16
    int arow[2], grow[2], brow[2], kch[2];
    #pragma unroll
    for (int i = 0; i < 2; ++i) {
        const int g  = i * 256 + tid;
        const int rr = g >> 2;
        kch[i] = (g & 3) << 3;
        int gr2 = r0 + rr;
        if (gr2 >= M) gr2 = M - 1;
        grow[i] = gr2;
        arow[i] = ridx0 ? ridx0[gr2] : gr2;
        brow[i] = c0 + rr;
    }
    unsigned short* AsW = &SM[0][wave * 512];   // +i*2048 shorts per inst
    unsigned short* BsW = &SM[1][wave * 512];

    floatx4 acc[4][4];
    #pragma unroll
    for (int i = 0; i < 4; ++i)
        #pragma unroll
        for (int j = 0; j < 4; ++j) acc[i][j] = (floatx4){0.f, 0.f, 0.f, 0.f};

    // hoisted B pointers (advance += 32 shorts per K-step)
    const unsigned short* pB0 = Wt + (long)brow[0] * K + kch[0];
    const unsigned short* pB1 = Wt + (long)brow[1] * K + kch[1];

    auto KSTEP = [&](const unsigned short* pA0, const unsigned short* pA1) {
        glds16(pA0, AsW);
        glds16(pB0, BsW);
        glds16(pA1, AsW + 2048);
        glds16(pB1, BsW + 2048);
        __syncthreads();

        short8 af[4], bfr[4];
        #pragma unroll
        for (int mt = 0; mt < 4; ++mt)
            af[mt] = *(const short8*)(&SM[0][(wm + mt * 16 + l16) * 32 + quad * 8]);
        #pragma unroll
        for (int nt = 0; nt < 4; ++nt)
            bfr[nt] = *(const short8*)(&SM[1][(wn + nt * 16 + l16) * 32 + quad * 8]);
        #pragma unroll
        for (int mt = 0; mt < 4; ++mt)
            #pragma unroll
            for (int nt = 0; nt < 4; ++nt)
                acc[mt][nt] = __builtin_amdgcn_mfma_f32_16x16x32_bf16(
                    af[mt], bfr[nt], acc[mt][nt], 0, 0, 0);
        __syncthreads();
        pB0 += 32; pB1 += 32;
    };

    int k0 = 0;
    const int Ka = (C0 < K) ? C0 : K;
    if (k0 < Ka) {                       // segment 0 (src0b)
        const unsigned short* pA0 = src0b + (long)arow[0] * s0 + o0 + kch[0];
        const unsigned short* pA1 = src0b + (long)arow[1] * s0 + o0 + kch[1];
        for (; k0 < Ka; k0 += 32) {
            KSTEP(pA0, pA1);
            pA0 += 32; pA1 += 32;
        }
    }
    if (k0 < K) {                        // segment 1 (src1b), starts at k0==C0
        const unsigned short* pA0 = src1b + (long)grow[0] * s1 + o1 + kch[0];
        const unsigned short* pA1 = src1b + (long)grow[1] * s1 + o1 + kch[1];
        for (; k0 < K; k0 += 32) {
            KSTEP(pA0, pA1);
            pA0 += 32; pA1 += 32;
        }
    }

    if (outf) {
        #pragma unroll
        for (int nt = 0; nt < 4; ++nt) {
            const int gc = c0 + wn + nt * 16 + l16;
            const float bv = bias ? bias[gc] : 0.f;
            #pragma unroll
            for (int mt = 0; mt < 4; ++mt) {
                #pragma unroll
                for (int reg = 0; reg < 4; ++reg) {
                    const int grr = r0 + wm + mt * 16 + quad * 4 + reg;
                    if (grr < M) {
                        float v = acc[mt][nt][reg] + bv;
                        if (do_relu) v = fmaxf(v, 0.f);
                        outf[(long)grr * sof + oof + gc] = v;
                    }
                }
            }
        }
    }
    if (outb) {
        // bf16 path: LDS-staged coalesced epilogue, 2 passes of 64 rows.
        unsigned short* Cs = &SM[0][0];
        #pragma unroll
        for (int p = 0; p < 2; ++p) {
            if (wm == p * 64) {
                #pragma unroll
                for (int nt = 0; nt < 4; ++nt) {
                    const int col = wn + nt * 16 + l16;
                    const float bv = bias ? bias[c0 + col] : 0.f;
                    #pragma unroll
                    for (int mt = 0; mt < 4; ++mt) {
                        #pragma unroll
                        for (int reg = 0; reg < 4; ++reg) {
                            float v = acc[mt][nt][reg] + bv;
                            if (do_relu) v = fmaxf(v, 0.f);
                            Cs[(mt * 16 + quad * 4 + reg) * 128 + col] = f2bf(v);
                        }
                    }
                }
            }
            __syncthreads();
            const int rl  = tid >> 2;
            const int cc0 = (tid & 3) << 3;
            const int grr2 = r0 + p * 64 + rl;
            if (grr2 < M) {
                const long rowbase = (rmode == 2)
                    ? ((long)(c0 >> 8) * ((long)N_EDGES * 256)
                       + (long)grr2 * 256 + (c0 & 255))
                    : ((long)grr2 * sob + oob + c0);
                #pragma unroll
                for (int j = 0; j < 4; ++j)
                    *(ushort8*)(outb + rowbase + cc0 + j * 32) =
                        *(const ushort8*)(&Cs[rl * 128 + cc0 + j * 32]);
            }
            __syncthreads();
        }
    }
}

// ---------------------------------------------------------------------------
// Aggregation: one wave per dst node, TWO edges in flight (named slots A/B).
// Summation order identical to serial loop -> bitwise-identical results.
// ---------------------------------------------------------------------------
__global__ __launch_bounds__(256) void agg_kernel(
    const unsigned short* __restrict__ pq,
    const int* __restrict__ rowptr,
    const int* __restrict__ ssrc,
    const float* __restrict__ sew,
    const unsigned short* __restrict__ Rb,
    const float* __restrict__ resid,
    const float* __restrict__ bias,
    float* __restrict__ out, int fofs, int rofs,
    unsigned short* __restrict__ nfbf, int nofs)
{
    const int wid  = (blockIdx.x * blockDim.x + threadIdx.x) >> 6;
    const int lane = threadIdx.x & 63;
    if (wid >= N_NODES) return;
    const int c = lane * 4;

    const ushort4v p4 = *(const ushort4v*)(pq + (long)wid * 512 + c);
    const float4 bb = *(const float4*)(bias + c);
    float pb[4] = {bf2f(p4[0]) + bb.x, bf2f(p4[1]) + bb.y,
                   bf2f(p4[2]) + bb.z, bf2f(p4[3]) + bb.w};
    float acc[4] = {0.f, 0.f, 0.f, 0.f};

    int s = rowptr[wid];
    const int sEnd = rowptr[wid + 1];

    ushort4v qA, rA, qB, rB;
    float wA = 0.f, wB = 0.f;
    if (s < sEnd) {
        const int n_ = ssrc[s];
        wA = sew[s];
        qA = *(const ushort4v*)(pq + (long)n_ * 512 + 256 + c);
        rA = *(const ushort4v*)(Rb + (long)s * 256 + c);
    }
    if (s + 1 < sEnd) {
        const int n_ = ssrc[s + 1];
        wB = sew[s + 1];
        qB = *(const ushort4v*)(pq + (long)n_ * 512 + 256 + c);
        rB = *(const ushort4v*)(Rb + (long)(s + 1) * 256 + c);
    }
    while (s + 1 < sEnd) {
        #pragma unroll
        for (int j = 0; j < 4; ++j)
            acc[j] += fmaxf(pb[j] + bf2f(qA[j]) + bf2f(rA[j]), 0.f) * wA;
        if (s + 2 < sEnd) {
            const int n_ = ssrc[s + 2];
            wA = sew[s + 2];
            qA = *(const ushort4v*)(pq + (long)n_ * 512 + 256 + c);
            rA = *(const ushort4v*)(Rb + (long)(s + 2) * 256 + c);
        }
        #pragma unroll
        for (int j = 0; j < 4; ++j)
            acc[j] += fmaxf(pb[j] + bf2f(qB[j]) + bf2f(rB[j]), 0.f) * wB;
        if (s + 3 < sEnd) {
            const int n_ = ssrc[s + 3];
            wB = sew[s + 3];
            qB = *(const ushort4v*)(pq + (long)n_ * 512 + 256 + c);
            rB = *(const ushort4v*)(Rb + (long)(s + 3) * 256 + c);
        }
        s += 2;
    }
    if (s < sEnd) {
        #pragma unroll
        for (int j = 0; j < 4; ++j)
            acc[j] += fmaxf(pb[j] + bf2f(qA[j]) + bf2f(rA[j]), 0.f) * wA;
    }
    if (rofs >= 0) {
        const float4 f4 = *(const float4*)(resid + (long)wid * OUT_STRIDE + rofs + c);
        acc[0] += f4.x; acc[1] += f4.y; acc[2] += f4.z; acc[3] += f4.w;
    }
    float4 o; o.x = acc[0]; o.y = acc[1]; o.z = acc[2]; o.w = acc[3];
    *(float4*)(out + (long)wid * OUT_STRIDE + fofs + c) = o;
    ushort4v hb = (ushort4v){f2bf(acc[0]), f2bf(acc[1]), f2bf(acc[2]), f2bf(acc[3])};
    *(ushort4v*)(nfbf + (long)wid * FD + nofs + c) = hb;
}

// ---------------------------------------------------------------------------
// Mega prep kernel: zeroing + both f32->bf16 converts + all weight preps in
// ONE launch. Flat region decode on blockIdx.x.
// ---------------------------------------------------------------------------
__device__ __forceinline__ void tr_block(const float* inp, unsigned short* outp,
                                         int K, int N, int bidx, int tid,
                                         float (*tile)[33])
{
    const int nbx = N >> 5;
    const int n0 = (bidx % nbx) << 5;
    const int k0 = (bidx / nbx) << 5;
    const int tx = tid & 31, ty = tid >> 5;
    #pragma unroll
    for (int r = 0; r < 4; ++r)
        tile[ty + r * 8][tx] = inp[(long)(k0 + ty + r * 8) * N + n0 + tx];
    __syncthreads();
    #pragma unroll
    for (int r = 0; r < 4; ++r)
        outp[(long)(n0 + ty + r * 8) * K + k0 + tx] = f2bf(tile[tx][ty + r * 8]);
}

#define PB_ZERO  79     // (20001 + 129 + 255)/256
#define PB_CVTX  1250
#define PB_CVTE  3125
#define PB_WPQ0  128
#define PB_WPQ3  384
#define PB_WTR   128
#define PB_TS0   80
#define PB_TS3   384
#define PB_TF    1024
#define PREP_BLOCKS (PB_ZERO+PB_CVTX+PB_CVTE+PB_WPQ0+PB_WPQ3+PB_WTR+PB_TS0+PB_TS3+PB_TF+PB_TF)

__global__ __launch_bounds__(256) void prep_all(
    const float* __restrict__ x, const float* __restrict__ ea,
    const float* __restrict__ W_msg0, const float* __restrict__ W_msg,
    const float* __restrict__ W_sup0, const float* __restrict__ W_sup,
    const float* __restrict__ W_fuse, const float* __restrict__ W_fsup,
    unsigned short* __restrict__ xb, unsigned short* __restrict__ eab,
    unsigned short* __restrict__ wpq0, unsigned short* __restrict__ wpq,
    unsigned short* __restrict__ wtr,
    unsigned short* __restrict__ wt_sup0, unsigned short* __restrict__ wt_sup,
    unsigned short* __restrict__ wt_fuse, unsigned short* __restrict__ wt_fsup,
    int* __restrict__ cnt, int* __restrict__ bcnt)
{
    __shared__ float tile[32][33];
    const int tid = threadIdx.x;
    int b = blockIdx.x;

    if (b < PB_ZERO) {                       // zero CSR counters
        int i = b * 256 + tid;
        if (i < N_NODES + 1) cnt[i] = 0;
        else if (i - (N_NODES + 1) < 129) bcnt[i - (N_NODES + 1)] = 0;
        return;
    }
    b -= PB_ZERO;
    if (b < PB_CVTX) {
        int i = b * 256 + tid;
        float4 v = ((const float4*)x)[i];
        ((ushort4v*)xb)[i] = (ushort4v){f2bf(v.x), f2bf(v.y), f2bf(v.z), f2bf(v.w)};
        return;
    }
    b -= PB_CVTX;
    if (b < PB_CVTE) {
        int i = b * 256 + tid;
        float4 v = ((const float4*)ea)[i];
        ((ushort4v*)eab)[i] = (ushort4v){f2bf(v.x), f2bf(v.y), f2bf(v.z), f2bf(v.w)};
        return;
    }
    b -= PB_CVTE;
    if (b < PB_WPQ0) {
        int i = b * 256 + tid;
        int nn = i >> 6, k = i & 63;
        float v = (nn < 256) ? (W_msg0[k * 256 + nn] - W_msg0[(64 + k) * 256 + nn])
                             : (W_msg0[(64 + k) * 256 + (nn - 256)]);
        wpq0[(long)nn * 64 + k] = f2bf(v);
        return;
    }
    b -= PB_WPQ0;
    if (b < PB_WPQ3) {
        const int slab = b / 128, bb = b % 128;
        const float* Wi = W_msg + (long)slab * 544 * 256;
        unsigned short* Wo = wpq + (long)slab * 512 * 256;
        const int n0 = (bb & 15) << 5;
        const int k0 = (bb >> 4) << 5;
        const int tx = tid & 31, ty = tid >> 5;
        #pragma unroll
        for (int r = 0; r < 4; ++r) {
            const int k = k0 + ty + r * 8;
            float v;
            if (n0 < 256)
                v = Wi[(long)k * 256 + n0 + tx] - Wi[(long)(256 + k) * 256 + n0 + tx];
            else
                v = Wi[(long)(256 + k) * 256 + (n0 - 256) + tx];
            tile[ty + r * 8][tx] = v;
        }
        __syncthreads();
        #pragma unroll
        for (int r = 0; r < 4; ++r)
            Wo[(long)(n0 + ty + r * 8) * 256 + k0 + tx] = f2bf(tile[tx][ty + r * 8]);
        return;
    }
    b -= PB_WPQ3;
    if (b < PB_WTR) {
        const int j = b >> 5;
        const float* Wi = (j == 0) ? (W_msg0 + 2 * CIN * 256)
                                   : (W_msg + (long)(j - 1) * 544 * 256 + 2 * CCH * 256);
        unsigned short* Wo = wtr + (long)j * 256 * 32;
        int i = (b & 31) * 256 + tid;
        int k = i >> 8, n = i & 255;
        Wo[(long)n * 32 + k] = f2bf(Wi[i]);
        return;
    }
    b -= PB_WTR;
    if (b < PB_TS0) { tr_block(W_sup0, wt_sup0, 320, 256, b, tid, tile); return; }
    b -= PB_TS0;
    if (b < PB_TS3) {
        const int slab = b / 128;
        tr_block(W_sup + (long)slab * 512 * 256, wt_sup + (long)slab * 256 * 512,
                 512, 256, b % 128, tid, tile);
        return;
    }
    b -= PB_TS3;
    if (b < PB_TF) { tr_block(W_fuse, wt_fuse, 1024, 1024, b, tid, tile); return; }
    b -= PB_TF;
    tr_block(W_fsup, wt_fsup, 1024, 1024, b, tid, tile);
}

// ---------------------------------------------------------------------------
// CSR build (edge + box variants merged per stage)
// ---------------------------------------------------------------------------
__global__ void hist2(const int* __restrict__ dst, const int* __restrict__ bbox,
                      int* __restrict__ cnt, int* __restrict__ bcnt) {
    int i = blockIdx.x * blockDim.x + threadIdx.x;
    if (i < N_EDGES) atomicAdd(&cnt[dst[i]], 1);
    else if (i - N_EDGES < N_NODES) atomicAdd(&bcnt[bbox[i - N_EDGES]], 1);
}
__global__ __launch_bounds__(1024) void scan2(
    const int* __restrict__ cnt,  int* __restrict__ rowptr, int* __restrict__ ofs,
    const int* __restrict__ bcnt, int* __restrict__ bptr,   int* __restrict__ bofs)
{
    __shared__ int part[1024];
    const int tid = threadIdx.x;
    const int n = blockIdx.x == 0 ? N_NODES : NBOX;
    const int* c   = blockIdx.x == 0 ? cnt    : bcnt;
    int* rp        = blockIdx.x == 0 ? rowptr : bptr;
    int* op        = blockIdx.x == 0 ? ofs    : bofs;
    const int chunk = (n + 1023) >> 10;
    int s = 0;
    for (int j = 0; j < chunk; ++j) {
        int i = tid * chunk + j;
        if (i < n) s += c[i];
    }
    part[tid] = s; __syncthreads();
    for (int d = 1; d < 1024; d <<= 1) {
        int v = (tid >= d) ? part[tid - d] : 0;
        __syncthreads();
        part[tid] += v;
        __syncthreads();
    }
    int run = (tid > 0) ? part[tid - 1] : 0;
    for (int j = 0; j < chunk; ++j) {
        int i = tid * chunk + j;
        if (i < n) { rp[i] = run; op[i] = run; run += c[i]; }
    }
    if (tid == 1023) rp[n] = part[1023];
}
__global__ void scatter2(const int* __restrict__ src, const int* __restrict__ dst,
                         const float* __restrict__ ew, int* __restrict__ ofs,
                         int* __restrict__ ssrc, float* __restrict__ sew,
                         int* __restrict__ seid,
                         const int* __restrict__ bbox, int* __restrict__ bofs,
                         int* __restrict__ snode) {
    int i = blockIdx.x * blockDim.x + threadIdx.x;
    if (i < N_EDGES) {
        int pos = atomicAdd(&ofs[dst[i]], 1);
        ssrc[pos] = src[i];
        sew[pos]  = ew[i];
        seid[pos] = i;
    } else if (i - N_EDGES < N_NODES) {
        int j = i - N_EDGES;
        int pos = atomicAdd(&bofs[bbox[j]], 1);
        snode[pos] = j;
    }
}

// ---------------------------------------------------------------------------
// Box mean via CSR, 1-deep gather prefetch. Emits fp32 + bf16 fsmean.
// ---------------------------------------------------------------------------
__global__ __launch_bounds__(256) void box_mean_csr(
    const unsigned short* __restrict__ fsbf, const int* __restrict__ bptr,
    const int* __restrict__ snode, float* __restrict__ out_super,
    unsigned short* __restrict__ fsmeanb)
{
    const int b = blockIdx.x >> 2;
    const int c = ((blockIdx.x & 3) << 8) + threadIdx.x;
    const int s0 = bptr[b], s1 = bptr[b + 1];
    float sum = 0.f;
    int s = s0;
    unsigned short hn = 0;
    if (s < s1) hn = fsbf[(long)snode[s] * FD + c];
    while (s < s1) {
        const unsigned short h = hn;
        if (s + 1 < s1) hn = fsbf[(long)snode[s + 1] * FD + c];
        sum += bf2f(h);
        ++s;
    }
    const float mean = sum / fmaxf((float)(s1 - s0), 1.f);
    out_super[(long)b * OUT_STRIDE + HID + c] = mean;
    fsmeanb[(long)b * FD + c] = f2bf(mean);
}

// ---------------------------------------------------------------------------
extern "C" void kernel_launch(void* const* d_in, const int* in_sizes, int n_in,
                              void* d_out, int out_size, void* d_ws, size_t ws_size,
                              hipStream_t stream) {
    const float* x      = (const float*)d_in[0];
    const int*   edges  = (const int*)d_in[1];
    const float* ew     = (const float*)d_in[2];
    const float* ea     = (const float*)d_in[3];
    const int*   bbox   = (const int*)d_in[4];
    const float* W_msg0 = (const float*)d_in[6];
    const float* b_msg0 = (const float*)d_in[7];
    const float* W_sup0 = (const float*)d_in[8];
    const float* b_sup0 = (const float*)d_in[9];
    const float* W_msg  = (const float*)d_in[10];
    const float* b_msg  = (const float*)d_in[11];
    const float* W_sup  = (const float*)d_in[12];
    const float* b_sup  = (const float*)d_in[13];
    const float* W_fuse = (const float*)d_in[14];
    const float* b_fuse = (const float*)d_in[15];
    const float* W_fsup = (const float*)d_in[16];
    const float* b_fsup = (const float*)d_in[17];

    float* out       = (float*)d_out;
    float* out_super = out + (long)N_NODES * OUT_STRIDE;

    // ---- workspace layout ----
    char* w = (char*)d_ws;
    auto alloc = [&](size_t bytes) { char* p = w; w += (bytes + 63) & ~63ULL; return p; };
    unsigned short* fsbf    = (unsigned short*)alloc((size_t)N_NODES * FD * 2);
    unsigned short* nfbf    = (unsigned short*)alloc((size_t)N_NODES * FD * 2);
    unsigned short* pq      = (unsigned short*)alloc((size_t)N_NODES * 512 * 2);
    unsigned short* xb      = (unsigned short*)alloc((size_t)N_NODES * CIN * 2);
    unsigned short* eab     = (unsigned short*)alloc((size_t)N_EDGES * A_DIM * 2);
    unsigned short* Rb4     = (unsigned short*)alloc((size_t)N_EDGES * 1024 * 2);
    unsigned short* wpq0    = (unsigned short*)alloc((size_t)512 * CIN * 2);
    unsigned short* wpq     = (unsigned short*)alloc((size_t)3 * 512 * CCH * 2);
    unsigned short* wtr     = (unsigned short*)alloc((size_t)4 * 256 * 32 * 2);
    unsigned short* wt_sup0 = (unsigned short*)alloc((size_t)256 * 320 * 2);
    unsigned short* wt_sup  = (unsigned short*)alloc((size_t)3 * 256 * 512 * 2);
    unsigned short* wt_fuse = (unsigned short*)alloc((size_t)1024 * 1024 * 2);
    unsigned short* wt_fsup = (unsigned short*)alloc((size_t)1024 * 1024 * 2);
    unsigned short* fsmeanb = (unsigned short*)alloc((size_t)NBOX * FD * 2);
    float* sew        = (float*)alloc((size_t)N_EDGES * 4);
    int* cnt          = (int*)alloc((size_t)(N_NODES + 1) * 4);
    int* rowptr       = (int*)alloc((size_t)(N_NODES + 1) * 4);
    int* ofs          = (int*)alloc((size_t)(N_NODES + 1) * 4);
    int* ssrc         = (int*)alloc((size_t)N_EDGES * 4);
    int* seid         = (int*)alloc((size_t)N_EDGES * 4);
    int* bcnt         = (int*)alloc(129 * 4);
    int* bptr         = (int*)alloc(129 * 4);
    int* bofs         = (int*)alloc(129 * 4);
    int* snode        = (int*)alloc((size_t)N_NODES * 4);

    const int* srcp = edges;
    const int* dstp = edges + N_EDGES;

    // ---- prep + CSR-zero (1 launch) ----
    prep_all<<<PREP_BLOCKS, 256, 0, stream>>>(
        x, ea, W_msg0, W_msg, W_sup0, W_sup, W_fuse, W_fsup,
        xb, eab, wpq0, wpq, wtr, wt_sup0, wt_sup, wt_fuse, wt_fsup,
        cnt, bcnt);

    // ---- CSR build (3 launches) ----
    hist2<<<(N_EDGES + N_NODES + 255) / 256, 256, 0, stream>>>(dstp, bbox, cnt, bcnt);
    scan2<<<2, 1024, 0, stream>>>(cnt, rowptr, ofs, bcnt, bptr, bofs);
    scatter2<<<(N_EDGES + N_NODES + 255) / 256, 256, 0, stream>>>(
        srcp, dstp, ew, ofs, ssrc, sew, seid, bbox, bofs, snode);

    const int GRB = (N_NODES + 127) / 128;   // 157
    const int GEB = (N_EDGES + 127) / 128;   // 782
    const long RLS = (long)N_EDGES * 256;    // R layer stride (shorts)

    auto mk = [](const unsigned short* src0b, int s0, int o0, int C0,
                 const int* ridx0,
                 const unsigned short* src1b, int s1, int o1,
                 const unsigned short* Wt, const float* bias, int relu,
                 float* outf, int sof, int oof,
                 unsigned short* outb, int sob, int oob, int rmode,
                 int M, int K, int nbc) {
        GD g;
        g.src0b = src0b; g.s0 = s0; g.o0 = o0; g.C0 = C0;
        g.ridx0 = ridx0;
        g.src1b = src1b; g.s1 = s1; g.o1 = o1;
        g.Wt = Wt; g.bias = bias; g.do_relu = relu;
        g.outf = outf; g.sof = sof; g.oof = oof;
        g.outb = outb; g.sob = sob; g.oob = oob; g.rmode = rmode;
        g.M = M; g.K = K; g.nbc = nbc;
        return g;
    };

    GD gR   = mk(eab, A_DIM, 0, A_DIM, seid, nullptr, 0, 0, wtr, nullptr, 0,
                 nullptr, 0, 0, Rb4, 0, 0, 2, N_EDGES, A_DIM, 8);
    GD gPQh = mk(xb, CIN, 0, CIN, nullptr, nullptr, 0, 0, wpq0, nullptr, 0,
                 nullptr, 0, 0, pq, 512, 0, 0, N_NODES, CIN, 4);
    GD gS0  = mk(nfbf, FD, 0, CCH, nullptr, xb, CIN, 0, wt_sup0, b_sup0, 1,
                 nullptr, 0, 0, fsbf, FD, 0, 0, N_NODES, CCH + CIN, 2);
    GD gPQ[3], gS[3];
    for (int i = 0; i < 3; ++i) {
        gPQ[i] = mk(nfbf, FD, CCH * i, CCH, nullptr, nullptr, 0, 0,
                    wpq + (long)i * 512 * CCH, nullptr, 0,
                    nullptr, 0, 0, pq, 512, 0, 0, N_NODES, CCH, 4);
        gS[i]  = mk(nfbf, FD, CCH * (i + 1), CCH, nullptr, fsbf, FD, CCH * i,
                    wt_sup + (long)i * 256 * 512, b_sup + i * CCH, 1,
                    nullptr, 0, 0, fsbf, FD, CCH * (i + 1), 0, N_NODES, 2 * CCH, 2);
    }
    GD gFU  = mk(nfbf, FD, 0, FD, nullptr, nullptr, 0, 0, wt_fuse, b_fuse, 1,
                 out, OUT_STRIDE, 0, nullptr, 0, 0, 0, N_NODES, FD, 8);
    GD gFS  = mk(fsmeanb, FD, 0, FD, nullptr, nullptr, 0, 0, wt_fsup, b_fsup, 1,
                 out_super, OUT_STRIDE, 0, nullptr, 0, 0, 0, NBOX, FD, 8);

    const int AGRID = (N_NODES + 3) / 4;

    // ---- R GEMM (all 4 layers) || head pq GEMM ----
    mfma_dense<<<GEB * 8 + GRB * 4, 256, 0, stream>>>(gR, gPQh, GEB * 8);

    // ---- head agg ----
    agg_kernel<<<AGRID, 256, 0, stream>>>(pq, rowptr, ssrc, sew,
        Rb4, out, b_msg0, out, HID, -1, nfbf, 0);

    // ---- [sup_head || pq_res0] -> agg_res0 -> [sup_res0 || pq_res1] -> ... ----
    mfma_dense<<<GRB * 6, 256, 0, stream>>>(gS0, gPQ[0], GRB * 2);
    for (int i = 0; i < 3; ++i) {
        agg_kernel<<<AGRID, 256, 0, stream>>>(pq, rowptr, ssrc, sew,
            Rb4 + (long)(i + 1) * RLS, out, b_msg + i * CCH,
            out, HID + CCH * (i + 1), HID + CCH * i, nfbf, CCH * (i + 1));
        if (i < 2)
            mfma_dense<<<GRB * 6, 256, 0, stream>>>(gS[i], gPQ[i + 1], GRB * 2);
    }

    // ---- [sup_res2 || fusion] ----
    mfma_dense<<<GRB * 10, 256, 0, stream>>>(gS[2], gFU, GRB * 2);

    // ---- super path ----
    box_mean_csr<<<NBOX * 4, 256, 0, stream>>>(fsbf, bptr, snode, out_super, fsmeanb);
    mfma_dense<<<8, 256, 0, stream>>>(gFS, gFS, 8);
}

// Round 12
// 754.378 us; speedup vs baseline: 1.0687x; 1.0366x over previous
//
#include <hip/hip_runtime.h>

#define N_NODES 20000
#define N_EDGES 100000
#define CIN     64
#define A_DIM   32
#define CCH     256
#define NBOX    128
#define FD      1024
#define HID     1024
#define OUT_STRIDE 2048

typedef __attribute__((ext_vector_type(8))) short          short8;
typedef __attribute__((ext_vector_type(8))) unsigned short ushort8;
typedef __attribute__((ext_vector_type(4))) unsigned short ushort4v;
typedef __attribute__((ext_vector_type(4))) float          floatx4;

__device__ __forceinline__ unsigned short f2bf(float f) {
    unsigned int u = __float_as_uint(f);
    u += 0x7fff + ((u >> 16) & 1);
    return (unsigned short)(u >> 16);
}
__device__ __forceinline__ float bf2f(unsigned short h) {
    return __uint_as_float(((unsigned int)h) << 16);
}

// async global->LDS, 16B per lane; LDS dest is wave-uniform base + lane*16
__device__ __forceinline__ void glds16(const unsigned short* g, unsigned short* l) {
    __builtin_amdgcn_global_load_lds(
        (const __attribute__((address_space(1))) unsigned int*)g,
        (__attribute__((address_space(3))) unsigned int*)l,
        16, 0, 0);
}

// ---------------------------------------------------------------------------
// GEMM descriptor (dual-dispatch support: one launch can carry two GEMMs).
// 128x128 tile, BK=32, DOUBLE-BUFFERED staging with counted vmcnt + raw
// s_barrier (T4): stage(t+1) stays in flight across the pre-compute barrier
// (s_waitcnt vmcnt(4), not the compiler's vmcnt(0) drain), so tile fetch
// latency overlaps tile-t MFMA. Regime justification: occupancy ~8 waves/CU
// (r9 counters) -> wave-TLP cannot hide latency; intra-wave pipeline must.
// Correctness: vmcnt(4) retires each wave's OWN tile-t loads (FIFO) before
// barrier1 -> all tile-t data in LDS; stage(t+2) issues only after barrier2,
// which every wave passes after lgkmcnt(0) landed its reads (no WAR race).
// Measured dead ends -- do not revisit: 128x256 tile (acc->AGPR, 1 wave/SIMD,
// 2x regression, r8); BK=64+swizzle (occupancy drop, net -3%, r10).
// ---------------------------------------------------------------------------
struct GD {
    const unsigned short* src0b;
    const unsigned short* src1b;
    const unsigned short* Wt;
    const float* bias;
    const int* ridx0;
    float* outf;
    unsigned short* outb;
    int s0, o0, C0, s1, o1, do_relu, sof, oof, sob, oob, rmode, M, K, nbc;
};

__global__ __launch_bounds__(256) void mfma_dense(GD A, GD B, int n0)
{
    // 32KB: A-buf b at [b*4096], B-buf b at [8192 + b*4096] (shorts)
    __shared__ __align__(16) unsigned short SM[16384];

    const int tid = threadIdx.x;
    const bool fa = (int)blockIdx.x < n0;

    const unsigned short* src0b = fa ? A.src0b : B.src0b;
    const unsigned short* src1b = fa ? A.src1b : B.src1b;
    const unsigned short* Wt    = fa ? A.Wt    : B.Wt;
    const float* bias           = fa ? A.bias  : B.bias;
    const int*   ridx0          = fa ? A.ridx0 : B.ridx0;
    float* outf                 = fa ? A.outf  : B.outf;
    unsigned short* outb        = fa ? A.outb  : B.outb;
    const int s0  = fa ? A.s0  : B.s0,  o0  = fa ? A.o0  : B.o0;
    const int C0  = fa ? A.C0  : B.C0;
    const int s1  = fa ? A.s1  : B.s1,  o1  = fa ? A.o1  : B.o1;
    const int do_relu = fa ? A.do_relu : B.do_relu;
    const int sof = fa ? A.sof : B.sof, oof = fa ? A.oof : B.oof;
    const int sob = fa ? A.sob : B.sob, oob = fa ? A.oob : B.oob;
    const int rmode = fa ? A.rmode : B.rmode;
    const int M   = fa ? A.M   : B.M;
    const int K   = fa ? A.K   : B.K;
    const int nbc = fa ? A.nbc : B.nbc;

    // bijective XCD swizzle within this descriptor's sub-grid
    const int nwg = fa ? n0 : (int)gridDim.x - n0;
    const int lb  = (int)blockIdx.x - (fa ? 0 : n0);
    const int q8  = nwg >> 3, r8 = nwg & 7;
    const int xcd = lb & 7, boff = lb >> 3;
    const int bid = (xcd < r8 ? xcd * (q8 + 1)
                              : r8 * (q8 + 1) + (xcd - r8) * q8) + boff;

    const int rb   = bid / nbc, cb = bid % nbc;
    const int r0   = rb * 128, c0 = cb * 128;
    const int wave = tid >> 6, lane = tid & 63;
    const int quad = lane >> 4, l16 = lane & 15;
    const int wm   = (wave & 1) * 64, wn = (wave >> 1) * 64;

    // staging slot geometry: slot g = i*256 + tid covers LDS bytes [g*16, g*16+16)
    // row = g>>2 (64B rows), k-chunk = (g&3)*8 bf16
    int arow[2], grow[2], brow[2], kch[2];
    #pragma unroll
    for (int i = 0; i < 2; ++i) {
        const int g  = i * 256 + tid;
        const int rr = g >> 2;
        kch[i] = (g & 3) << 3;
        int gr2 = r0 + rr;
        if (gr2 >= M) gr2 = M - 1;
        grow[i] = gr2;
        arow[i] = ridx0 ? ridx0[gr2] : gr2;
        brow[i] = c0 + rr;
    }

    floatx4 acc[4][4];
    #pragma unroll
    for (int i = 0; i < 4; ++i)
        #pragma unroll
        for (int j = 0; j < 4; ++j) acc[i][j] = (floatx4){0.f, 0.f, 0.f, 0.f};

    auto stage_tile = [&](int ts) {
        const int kk = ts << 5;
        const unsigned short *a0, *a1;
        if (kk < C0) {
            a0 = src0b + (long)arow[0] * s0 + o0 + kk + kch[0];
            a1 = src0b + (long)arow[1] * s0 + o0 + kk + kch[1];
        } else {
            a0 = src1b + (long)grow[0] * s1 + o1 + (kk - C0) + kch[0];
            a1 = src1b + (long)grow[1] * s1 + o1 + (kk - C0) + kch[1];
        }
        const unsigned short* b0 = Wt + (long)brow[0] * K + kk + kch[0];
        const unsigned short* b1 = Wt + (long)brow[1] * K + kk + kch[1];
        const int buf = ts & 1;
        glds16(a0, &SM[buf * 4096 + wave * 512]);
        glds16(b0, &SM[8192 + buf * 4096 + wave * 512]);
        glds16(a1, &SM[buf * 4096 + wave * 512 + 2048]);
        glds16(b1, &SM[8192 + buf * 4096 + wave * 512 + 2048]);
    };

    const int NT = K >> 5;
    stage_tile(0);
    if (NT > 1) stage_tile(1);

    for (int t = 0; t < NT; ++t) {
        // barrier1: tile-t data ready everywhere; tile-(t+1) loads stay in flight
        if (t + 1 < NT)
            asm volatile("s_waitcnt vmcnt(4)" ::: "memory");
        else
            asm volatile("s_waitcnt vmcnt(0)" ::: "memory");
        __builtin_amdgcn_s_barrier();
        __builtin_amdgcn_sched_barrier(0);

        const int buf = t & 1;
        short8 af[4], bfr[4];
        #pragma unroll
        for (int mt = 0; mt < 4; ++mt)
            af[mt] = *(const short8*)(
                &SM[buf * 4096 + (wm + mt * 16 + l16) * 32 + quad * 8]);
        #pragma unroll
        for (int nt = 0; nt < 4; ++nt)
            bfr[nt] = *(const short8*)(
                &SM[8192 + buf * 4096 + (wn + nt * 16 + l16) * 32 + quad * 8]);
        #pragma unroll
        for (int mt = 0; mt < 4; ++mt)
            #pragma unroll
            for (int nt = 0; nt < 4; ++nt)
                acc[mt][nt] = __builtin_amdgcn_mfma_f32_16x16x32_bf16(
                    af[mt], bfr[nt], acc[mt][nt], 0, 0, 0);

        // barrier2: my ds_read data landed (lgkmcnt 0) -> buf[t&1] free for t+2
        asm volatile("s_waitcnt lgkmcnt(0)" ::: "memory");
        __builtin_amdgcn_sched_barrier(0);
        __builtin_amdgcn_s_barrier();
        if (t + 2 < NT) stage_tile(t + 2);
    }

    if (outf) {
        #pragma unroll
        for (int nt = 0; nt < 4; ++nt) {
            const int gc = c0 + wn + nt * 16 + l16;
            const float bv = bias ? bias[gc] : 0.f;
            #pragma unroll
            for (int mt = 0; mt < 4; ++mt) {
                #pragma unroll
                for (int reg = 0; reg < 4; ++reg) {
                    const int grr = r0 + wm + mt * 16 + quad * 4 + reg;
                    if (grr < M) {
                        float v = acc[mt][nt][reg] + bv;
                        if (do_relu) v = fmaxf(v, 0.f);
                        outf[(long)grr * sof + oof + gc] = v;
                    }
                }
            }
        }
    }
    if (outb) {
        // bf16 path: LDS-staged coalesced epilogue, 2 passes of 64 rows.
        unsigned short* Cs = &SM[0];       // 64*128 shorts, fits in buf region
        __syncthreads();                   // all K-loop LDS traffic retired
        #pragma unroll
        for (int p = 0; p < 2; ++p) {
            if (wm == p * 64) {
                #pragma unroll
                for (int nt = 0; nt < 4; ++nt) {
                    const int col = wn + nt * 16 + l16;
                    const float bv = bias ? bias[c0 + col] : 0.f;
                    #pragma unroll
                    for (int mt = 0; mt < 4; ++mt) {
                        #pragma unroll
                        for (int reg = 0; reg < 4; ++reg) {
                            float v = acc[mt][nt][reg] + bv;
                            if (do_relu) v = fmaxf(v, 0.f);
                            Cs[(mt * 16 + quad * 4 + reg) * 128 + col] = f2bf(v);
                        }
                    }
                }
            }
            __syncthreads();
            const int rl  = tid >> 2;
            const int cc0 = (tid & 3) << 3;
            const int grr2 = r0 + p * 64 + rl;
            if (grr2 < M) {
                const long rowbase = (rmode == 2)
                    ? ((long)(c0 >> 8) * ((long)N_EDGES * 256)
                       + (long)grr2 * 256 + (c0 & 255))
                    : ((long)grr2 * sob + oob + c0);
                #pragma unroll
                for (int j = 0; j < 4; ++j)
                    *(ushort8*)(outb + rowbase + cc0 + j * 32) =
                        *(const ushort8*)(&Cs[rl * 128 + cc0 + j * 32]);
            }
            __syncthreads();
        }
    }
}

// ---------------------------------------------------------------------------
// Aggregation: one wave per dst node, TWO edges in flight (named slots A/B).
// Summation order identical to serial loop -> bitwise-identical results.
// ---------------------------------------------------------------------------
__global__ __launch_bounds__(256) void agg_kernel(
    const unsigned short* __restrict__ pq,
    const int* __restrict__ rowptr,
    const int* __restrict__ ssrc,
    const float* __restrict__ sew,
    const unsigned short* __restrict__ Rb,
    const float* __restrict__ resid,
    const float* __restrict__ bias,
    float* __restrict__ out, int fofs, int rofs,
    unsigned short* __restrict__ nfbf, int nofs)
{
    const int wid  = (blockIdx.x * blockDim.x + threadIdx.x) >> 6;
    const int lane = threadIdx.x & 63;
    if (wid >= N_NODES) return;
    const int c = lane * 4;

    const ushort4v p4 = *(const ushort4v*)(pq + (long)wid * 512 + c);
    const float4 bb = *(const float4*)(bias + c);
    float pb[4] = {bf2f(p4[0]) + bb.x, bf2f(p4[1]) + bb.y,
                   bf2f(p4[2]) + bb.z, bf2f(p4[3]) + bb.w};
    float acc[4] = {0.f, 0.f, 0.f, 0.f};

    int s = rowptr[wid];
    const int sEnd = rowptr[wid + 1];

    ushort4v qA, rA, qB, rB;
    float wA = 0.f, wB = 0.f;
    if (s < sEnd) {
        const int n_ = ssrc[s];
        wA = sew[s];
        qA = *(const ushort4v*)(pq + (long)n_ * 512 + 256 + c);
        rA = *(const ushort4v*)(Rb + (long)s * 256 + c);
    }
    if (s + 1 < sEnd) {
        const int n_ = ssrc[s + 1];
        wB = sew[s + 1];
        qB = *(const ushort4v*)(pq + (long)n_ * 512 + 256 + c);
        rB = *(const ushort4v*)(Rb + (long)(s + 1) * 256 + c);
    }
    while (s + 1 < sEnd) {
        #pragma unroll
        for (int j = 0; j < 4; ++j)
            acc[j] += fmaxf(pb[j] + bf2f(qA[j]) + bf2f(rA[j]), 0.f) * wA;
        if (s + 2 < sEnd) {
            const int n_ = ssrc[s + 2];
            wA = sew[s + 2];
            qA = *(const ushort4v*)(pq + (long)n_ * 512 + 256 + c);
            rA = *(const ushort4v*)(Rb + (long)(s + 2) * 256 + c);
        }
        #pragma unroll
        for (int j = 0; j < 4; ++j)
            acc[j] += fmaxf(pb[j] + bf2f(qB[j]) + bf2f(rB[j]), 0.f) * wB;
        if (s + 3 < sEnd) {
            const int n_ = ssrc[s + 3];
            wB = sew[s + 3];
            qB = *(const ushort4v*)(pq + (long)n_ * 512 + 256 + c);
            rB = *(const ushort4v*)(Rb + (long)(s + 3) * 256 + c);
        }
        s += 2;
    }
    if (s < sEnd) {
        #pragma unroll
        for (int j = 0; j < 4; ++j)
            acc[j] += fmaxf(pb[j] + bf2f(qA[j]) + bf2f(rA[j]), 0.f) * wA;
    }
    if (rofs >= 0) {
        const float4 f4 = *(const float4*)(resid + (long)wid * OUT_STRIDE + rofs + c);
        acc[0] += f4.x; acc[1] += f4.y; acc[2] += f4.z; acc[3] += f4.w;
    }
    float4 o; o.x = acc[0]; o.y = acc[1]; o.z = acc[2]; o.w = acc[3];
    *(float4*)(out + (long)wid * OUT_STRIDE + fofs + c) = o;
    ushort4v hb = (ushort4v){f2bf(acc[0]), f2bf(acc[1]), f2bf(acc[2]), f2bf(acc[3])};
    *(ushort4v*)(nfbf + (long)wid * FD + nofs + c) = hb;
}

// ---------------------------------------------------------------------------
// Mega prep kernel: zeroing + both f32->bf16 converts + all weight preps in
// ONE launch. Flat region decode on blockIdx.x.
// ---------------------------------------------------------------------------
__device__ __forceinline__ void tr_block(const float* inp, unsigned short* outp,
                                         int K, int N, int bidx, int tid,
                                         float (*tile)[33])
{
    const int nbx = N >> 5;
    const int n0 = (bidx % nbx) << 5;
    const int k0 = (bidx / nbx) << 5;
    const int tx = tid & 31, ty = tid >> 5;
    #pragma unroll
    for (int r = 0; r < 4; ++r)
        tile[ty + r * 8][tx] = inp[(long)(k0 + ty + r * 8) * N + n0 + tx];
    __syncthreads();
    #pragma unroll
    for (int r = 0; r < 4; ++r)
        outp[(long)(n0 + ty + r * 8) * K + k0 + tx] = f2bf(tile[tx][ty + r * 8]);
}

#define PB_ZERO  79     // (20001 + 129 + 255)/256
#define PB_CVTX  1250
#define PB_CVTE  3125
#define PB_WPQ0  128
#define PB_WPQ3  384
#define PB_WTR   128
#define PB_TS0   80
#define PB_TS3   384
#define PB_TF    1024
#define PREP_BLOCKS (PB_ZERO+PB_CVTX+PB_CVTE+PB_WPQ0+PB_WPQ3+PB_WTR+PB_TS0+PB_TS3+PB_TF+PB_TF)

__global__ __launch_bounds__(256) void prep_all(
    const float* __restrict__ x, const float* __restrict__ ea,
    const float* __restrict__ W_msg0, const float* __restrict__ W_msg,
    const float* __restrict__ W_sup0, const float* __restrict__ W_sup,
    const float* __restrict__ W_fuse, const float* __restrict__ W_fsup,
    unsigned short* __restrict__ xb, unsigned short* __restrict__ eab,
    unsigned short* __restrict__ wpq0, unsigned short* __restrict__ wpq,
    unsigned short* __restrict__ wtr,
    unsigned short* __restrict__ wt_sup0, unsigned short* __restrict__ wt_sup,
    unsigned short* __restrict__ wt_fuse, unsigned short* __restrict__ wt_fsup,
    int* __restrict__ cnt, int* __restrict__ bcnt)
{
    __shared__ float tile[32][33];
    const int tid = threadIdx.x;
    int b = blockIdx.x;

    if (b < PB_ZERO) {                       // zero CSR counters
        int i = b * 256 + tid;
        if (i < N_NODES + 1) cnt[i] = 0;
        else if (i - (N_NODES + 1) < 129) bcnt[i - (N_NODES + 1)] = 0;
        return;
    }
    b -= PB_ZERO;
    if (b < PB_CVTX) {
        int i = b * 256 + tid;
        float4 v = ((const float4*)x)[i];
        ((ushort4v*)xb)[i] = (ushort4v){f2bf(v.x), f2bf(v.y), f2bf(v.z), f2bf(v.w)};
        return;
    }
    b -= PB_CVTX;
    if (b < PB_CVTE) {
        int i = b * 256 + tid;
        float4 v = ((const float4*)ea)[i];
        ((ushort4v*)eab)[i] = (ushort4v){f2bf(v.x), f2bf(v.y), f2bf(v.z), f2bf(v.w)};
        return;
    }
    b -= PB_CVTE;
    if (b < PB_WPQ0) {
        int i = b * 256 + tid;
        int nn = i >> 6, k = i & 63;
        float v = (nn < 256) ? (W_msg0[k * 256 + nn] - W_msg0[(64 + k) * 256 + nn])
                             : (W_msg0[(64 + k) * 256 + (nn - 256)]);
        wpq0[(long)nn * 64 + k] = f2bf(v);
        return;
    }
    b -= PB_WPQ0;
    if (b < PB_WPQ3) {
        const int slab = b / 128, bb = b % 128;
        const float* Wi = W_msg + (long)slab * 544 * 256;
        unsigned short* Wo = wpq + (long)slab * 512 * 256;
        const int n0 = (bb & 15) << 5;
        const int k0 = (bb >> 4) << 5;
        const int tx = tid & 31, ty = tid >> 5;
        #pragma unroll
        for (int r = 0; r < 4; ++r) {
            const int k = k0 + ty + r * 8;
            float v;
            if (n0 < 256)
                v = Wi[(long)k * 256 + n0 + tx] - Wi[(long)(256 + k) * 256 + n0 + tx];
            else
                v = Wi[(long)(256 + k) * 256 + (n0 - 256) + tx];
            tile[ty + r * 8][tx] = v;
        }
        __syncthreads();
        #pragma unroll
        for (int r = 0; r < 4; ++r)
            Wo[(long)(n0 + ty + r * 8) * 256 + k0 + tx] = f2bf(tile[tx][ty + r * 8]);
        return;
    }
    b -= PB_WPQ3;
    if (b < PB_WTR) {
        const int j = b >> 5;
        const float* Wi = (j == 0) ? (W_msg0 + 2 * CIN * 256)
                                   : (W_msg + (long)(j - 1) * 544 * 256 + 2 * CCH * 256);
        unsigned short* Wo = wtr + (long)j * 256 * 32;
        int i = (b & 31) * 256 + tid;
        int k = i >> 8, n = i & 255;
        Wo[(long)n * 32 + k] = f2bf(Wi[i]);
        return;
    }
    b -= PB_WTR;
    if (b < PB_TS0) { tr_block(W_sup0, wt_sup0, 320, 256, b, tid, tile); return; }
    b -= PB_TS0;
    if (b < PB_TS3) {
        const int slab = b / 128;
        tr_block(W_sup + (long)slab * 512 * 256, wt_sup + (long)slab * 256 * 512,
                 512, 256, b % 128, tid, tile);
        return;
    }
    b -= PB_TS3;
    if (b < PB_TF) { tr_block(W_fuse, wt_fuse, 1024, 1024, b, tid, tile); return; }
    b -= PB_TF;
    tr_block(W_fsup, wt_fsup, 1024, 1024, b, tid, tile);
}

// ---------------------------------------------------------------------------
// CSR build (edge + box variants merged per stage)
// ---------------------------------------------------------------------------
__global__ void hist2(const int* __restrict__ dst, const int* __restrict__ bbox,
                      int* __restrict__ cnt, int* __restrict__ bcnt) {
    int i = blockIdx.x * blockDim.x + threadIdx.x;
    if (i < N_EDGES) atomicAdd(&cnt[dst[i]], 1);
    else if (i - N_EDGES < N_NODES) atomicAdd(&bcnt[bbox[i - N_EDGES]], 1);
}
__global__ __launch_bounds__(1024) void scan2(
    const int* __restrict__ cnt,  int* __restrict__ rowptr, int* __restrict__ ofs,
    const int* __restrict__ bcnt, int* __restrict__ bptr,   int* __restrict__ bofs)
{
    __shared__ int part[1024];
    const int tid = threadIdx.x;
    const int n = blockIdx.x == 0 ? N_NODES : NBOX;
    const int* c   = blockIdx.x == 0 ? cnt    : bcnt;
    int* rp        = blockIdx.x == 0 ? rowptr : bptr;
    int* op        = blockIdx.x == 0 ? ofs    : bofs;
    const int chunk = (n + 1023) >> 10;
    int s = 0;
    for (int j = 0; j < chunk; ++j) {
        int i = tid * chunk + j;
        if (i < n) s += c[i];
    }
    part[tid] = s; __syncthreads();
    for (int d = 1; d < 1024; d <<= 1) {
        int v = (tid >= d) ? part[tid - d] : 0;
        __syncthreads();
        part[tid] += v;
        __syncthreads();
    }
    int run = (tid > 0) ? part[tid - 1] : 0;
    for (int j = 0; j < chunk; ++j) {
        int i = tid * chunk + j;
        if (i < n) { rp[i] = run; op[i] = run; run += c[i]; }
    }
    if (tid == 1023) rp[n] = part[1023];
}
__global__ void scatter2(const int* __restrict__ src, const int* __restrict__ dst,
                         const float* __restrict__ ew, int* __restrict__ ofs,
                         int* __restrict__ ssrc, float* __restrict__ sew,
                         int* __restrict__ seid,
                         const int* __restrict__ bbox, int* __restrict__ bofs,
                         int* __restrict__ snode) {
    int i = blockIdx.x * blockDim.x + threadIdx.x;
    if (i < N_EDGES) {
        int pos = atomicAdd(&ofs[dst[i]], 1);
        ssrc[pos] = src[i];
        sew[pos]  = ew[i];
        seid[pos] = i;
    } else if (i - N_EDGES < N_NODES) {
        int j = i - N_EDGES;
        int pos = atomicAdd(&bofs[bbox[j]], 1);
        snode[pos] = j;
    }
}

// ---------------------------------------------------------------------------
// Box mean via CSR, 1-deep gather prefetch. Emits fp32 + bf16 fsmean.
// ---------------------------------------------------------------------------
__global__ __launch_bounds__(256) void box_mean_csr(
    const unsigned short* __restrict__ fsbf, const int* __restrict__ bptr,
    const int* __restrict__ snode, float* __restrict__ out_super,
    unsigned short* __restrict__ fsmeanb)
{
    const int b = blockIdx.x >> 2;
    const int c = ((blockIdx.x & 3) << 8) + threadIdx.x;
    const int s0 = bptr[b], s1 = bptr[b + 1];
    float sum = 0.f;
    int s = s0;
    unsigned short hn = 0;
    if (s < s1) hn = fsbf[(long)snode[s] * FD + c];
    while (s < s1) {
        const unsigned short h = hn;
        if (s + 1 < s1) hn = fsbf[(long)snode[s + 1] * FD + c];
        sum += bf2f(h);
        ++s;
    }
    const float mean = sum / fmaxf((float)(s1 - s0), 1.f);
    out_super[(long)b * OUT_STRIDE + HID + c] = mean;
    fsmeanb[(long)b * FD + c] = f2bf(mean);
}

// ---------------------------------------------------------------------------
extern "C" void kernel_launch(void* const* d_in, const int* in_sizes, int n_in,
                              void* d_out, int out_size, void* d_ws, size_t ws_size,
                              hipStream_t stream) {
    const float* x      = (const float*)d_in[0];
    const int*   edges  = (const int*)d_in[1];
    const float* ew     = (const float*)d_in[2];
    const float* ea     = (const float*)d_in[3];
    const int*   bbox   = (const int*)d_in[4];
    const float* W_msg0 = (const float*)d_in[6];
    const float* b_msg0 = (const float*)d_in[7];
    const float* W_sup0 = (const float*)d_in[8];
    const float* b_sup0 = (const float*)d_in[9];
    const float* W_msg  = (const float*)d_in[10];
    const float* b_msg  = (const float*)d_in[11];
    const float* W_sup  = (const float*)d_in[12];
    const float* b_sup  = (const float*)d_in[13];
    const float* W_fuse = (const float*)d_in[14];
    const float* b_fuse = (const float*)d_in[15];
    const float* W_fsup = (const float*)d_in[16];
    const float* b_fsup = (const float*)d_in[17];

    float* out       = (float*)d_out;
    float* out_super = out + (long)N_NODES * OUT_STRIDE;

    // ---- workspace layout ----
    char* w = (char*)d_ws;
    auto alloc = [&](size_t bytes) { char* p = w; w += (bytes + 63) & ~63ULL; return p; };
    unsigned short* fsbf    = (unsigned short*)alloc((size_t)N_NODES * FD * 2);
    unsigned short* nfbf    = (unsigned short*)alloc((size_t)N_NODES * FD * 2);
    unsigned short* pq      = (unsigned short*)alloc((size_t)N_NODES * 512 * 2);
    unsigned short* xb      = (unsigned short*)alloc((size_t)N_NODES * CIN * 2);
    unsigned short* eab     = (unsigned short*)alloc((size_t)N_EDGES * A_DIM * 2);
    unsigned short* Rb4     = (unsigned short*)alloc((size_t)N_EDGES * 1024 * 2);
    unsigned short* wpq0    = (unsigned short*)alloc((size_t)512 * CIN * 2);
    unsigned short* wpq     = (unsigned short*)alloc((size_t)3 * 512 * CCH * 2);
    unsigned short* wtr     = (unsigned short*)alloc((size_t)4 * 256 * 32 * 2);
    unsigned short* wt_sup0 = (unsigned short*)alloc((size_t)256 * 320 * 2);
    unsigned short* wt_sup  = (unsigned short*)alloc((size_t)3 * 256 * 512 * 2);
    unsigned short* wt_fuse = (unsigned short*)alloc((size_t)1024 * 1024 * 2);
    unsigned short* wt_fsup = (unsigned short*)alloc((size_t)1024 * 1024 * 2);
    unsigned short* fsmeanb = (unsigned short*)alloc((size_t)NBOX * FD * 2);
    float* sew        = (float*)alloc((size_t)N_EDGES * 4);
    int* cnt          = (int*)alloc((size_t)(N_NODES + 1) * 4);
    int* rowptr       = (int*)alloc((size_t)(N_NODES + 1) * 4);
    int* ofs          = (int*)alloc((size_t)(N_NODES + 1) * 4);
    int* ssrc         = (int*)alloc((size_t)N_EDGES * 4);
    int* seid         = (int*)alloc((size_t)N_EDGES * 4);
    int* bcnt         = (int*)alloc(129 * 4);
    int* bptr         = (int*)alloc(129 * 4);
    int* bofs         = (int*)alloc(129 * 4);
    int* snode        = (int*)alloc((size_t)N_NODES * 4);

    const int* srcp = edges;
    const int* dstp = edges + N_EDGES;

    // ---- prep + CSR-zero (1 launch) ----
    prep_all<<<PREP_BLOCKS, 256, 0, stream>>>(
        x, ea, W_msg0, W_msg, W_sup0, W_sup, W_fuse, W_fsup,
        xb, eab, wpq0, wpq, wtr, wt_sup0, wt_sup, wt_fuse, wt_fsup,
        cnt, bcnt);

    // ---- CSR build (3 launches) ----
    hist2<<<(N_EDGES + N_NODES + 255) / 256, 256, 0, stream>>>(dstp, bbox, cnt, bcnt);
    scan2<<<2, 1024, 0, stream>>>(cnt, rowptr, ofs, bcnt, bptr, bofs);
    scatter2<<<(N_EDGES + N_NODES + 255) / 256, 256, 0, stream>>>(
        srcp, dstp, ew, ofs, ssrc, sew, seid, bbox, bofs, snode);

    const int GRB = (N_NODES + 127) / 128;   // 157
    const int GEB = (N_EDGES + 127) / 128;   // 782
    const long RLS = (long)N_EDGES * 256;    // R layer stride (shorts)

    auto mk = [](const unsigned short* src0b, int s0, int o0, int C0,
                 const int* ridx0,
                 const unsigned short* src1b, int s1, int o1,
                 const unsigned short* Wt, const float* bias, int relu,
                 float* outf, int sof, int oof,
                 unsigned short* outb, int sob, int oob, int rmode,
                 int M, int K, int nbc) {
        GD g;
        g.src0b = src0b; g.s0 = s0; g.o0 = o0; g.C0 = C0;
        g.ridx0 = ridx0;
        g.src1b = src1b; g.s1 = s1; g.o1 = o1;
        g.Wt = Wt; g.bias = bias; g.do_relu = relu;
        g.outf = outf; g.sof = sof; g.oof = oof;
        g.outb = outb; g.sob = sob; g.oob = oob; g.rmode = rmode;
        g.M = M; g.K = K; g.nbc = nbc;
        return g;
    };

    GD gR   = mk(eab, A_DIM, 0, A_DIM, seid, nullptr, 0, 0, wtr, nullptr, 0,
                 nullptr, 0, 0, Rb4, 0, 0, 2, N_EDGES, A_DIM, 8);
    GD gPQh = mk(xb, CIN, 0, CIN, nullptr, nullptr, 0, 0, wpq0, nullptr, 0,
                 nullptr, 0, 0, pq, 512, 0, 0, N_NODES, CIN, 4);
    GD gS0  = mk(nfbf, FD, 0, CCH, nullptr, xb, CIN, 0, wt_sup0, b_sup0, 1,
                 nullptr, 0, 0, fsbf, FD, 0, 0, N_NODES, CCH + CIN, 2);
    GD gPQ[3], gS[3];
    for (int i = 0; i < 3; ++i) {
        gPQ[i] = mk(nfbf, FD, CCH * i, CCH, nullptr, nullptr, 0, 0,
                    wpq + (long)i * 512 * CCH, nullptr, 0,
                    nullptr, 0, 0, pq, 512, 0, 0, N_NODES, CCH, 4);
        gS[i]  = mk(nfbf, FD, CCH * (i + 1), CCH, nullptr, fsbf, FD, CCH * i,
                    wt_sup + (long)i * 256 * 512, b_sup + i * CCH, 1,
                    nullptr, 0, 0, fsbf, FD, CCH * (i + 1), 0, N_NODES, 2 * CCH, 2);
    }
    GD gFU  = mk(nfbf, FD, 0, FD, nullptr, nullptr, 0, 0, wt_fuse, b_fuse, 1,
                 out, OUT_STRIDE, 0, nullptr, 0, 0, 0, N_NODES, FD, 8);
    GD gFS  = mk(fsmeanb, FD, 0, FD, nullptr, nullptr, 0, 0, wt_fsup, b_fsup, 1,
                 out_super, OUT_STRIDE, 0, nullptr, 0, 0, 0, NBOX, FD, 8);

    const int AGRID = (N_NODES + 3) / 4;

    // ---- R GEMM (all 4 layers) || head pq GEMM ----
    mfma_dense<<<GEB * 8 + GRB * 4, 256, 0, stream>>>(gR, gPQh, GEB * 8);

    // ---- head agg ----
    agg_kernel<<<AGRID, 256, 0, stream>>>(pq, rowptr, ssrc, sew,
        Rb4, out, b_msg0, out, HID, -1, nfbf, 0);

    // ---- [sup_head || pq_res0] -> agg_res0 -> [sup_res0 || pq_res1] -> ... ----
    mfma_dense<<<GRB * 6, 256, 0, stream>>>(gS0, gPQ[0], GRB * 2);
    for (int i = 0; i < 3; ++i) {
        agg_kernel<<<AGRID, 256, 0, stream>>>(pq, rowptr, ssrc, sew,
            Rb4 + (long)(i + 1) * RLS, out, b_msg + i * CCH,
            out, HID + CCH * (i + 1), HID + CCH * i, nfbf, CCH * (i + 1));
        if (i < 2)
            mfma_dense<<<GRB * 6, 256, 0, stream>>>(gS[i], gPQ[i + 1], GRB * 2);
    }

    // ---- [sup_res2 || fusion] ----
    mfma_dense<<<GRB * 10, 256, 0, stream>>>(gS[2], gFU, GRB * 2);

    // ---- super path ----
    box_mean_csr<<<NBOX * 4, 256, 0, stream>>>(fsbf, bptr, snode, out_super, fsmeanb);
    mfma_dense<<<8, 256, 0, stream>>>(gFS, gFS, 8);
}

// Round 13
// 747.639 us; speedup vs baseline: 1.0783x; 1.0090x over previous
//
#include <hip/hip_runtime.h>

#define N_NODES 20000
#define N_EDGES 100000
#define CIN     64
#define A_DIM   32
#define CCH     256
#define NBOX    128
#define FD      1024
#define HID     1024
#define OUT_STRIDE 2048

typedef __attribute__((ext_vector_type(8))) short          short8;
typedef __attribute__((ext_vector_type(8))) unsigned short ushort8;
typedef __attribute__((ext_vector_type(4))) unsigned short ushort4v;
typedef __attribute__((ext_vector_type(4))) float          floatx4;

__device__ __forceinline__ unsigned short f2bf(float f) {
    unsigned int u = __float_as_uint(f);
    u += 0x7fff + ((u >> 16) & 1);
    return (unsigned short)(u >> 16);
}
__device__ __forceinline__ float bf2f(unsigned short h) {
    return __uint_as_float(((unsigned int)h) << 16);
}

// async global->LDS, 16B per lane; LDS dest is wave-uniform base + lane*16
__device__ __forceinline__ void glds16(const unsigned short* g, unsigned short* l) {
    __builtin_amdgcn_global_load_lds(
        (const __attribute__((address_space(1))) unsigned int*)g,
        (__attribute__((address_space(3))) unsigned int*)l,
        16, 0, 0);
}

// ---------------------------------------------------------------------------
// GEMM descriptor (dual-dispatch support: one launch can carry two GEMMs).
// 128x128 tile, BK=32, TRIPLE-BUFFERED staging with counted vmcnt + ONE raw
// s_barrier per K-step (r12's 2-barrier dbuf gave -28us; the 3rd buffer lets
// stage(t+2) issue right after barrier1 -- it writes buf[(t+2)%3], which no
// wave reads or loads into at that point, so the WAR barrier2 is deleted).
// WAR proof: buf[(t+2)%3] was last read in compute(t-1); any wave at
// barrier(t) already consumed those ds_reads (MFMA operands require data
// landed), so all reads retired before the new glds writes. vmcnt(4) retires
// each wave's OWN tile-t loads (FIFO); tail uses vmcnt(0).
// T5 setprio(1) wraps the MFMA cluster (pipeline gives wave role-diversity,
// the measured prerequisite for setprio to pay).
// Measured dead ends -- do not revisit: 128x256 tile (acc->AGPR, 1 wave/SIMD,
// 2x regression, r8); BK=64+swizzle (occupancy drop, net -3%, r10).
// ---------------------------------------------------------------------------
struct GD {
    const unsigned short* src0b;
    const unsigned short* src1b;
    const unsigned short* Wt;
    const float* bias;
    const int* ridx0;
    float* outf;
    unsigned short* outb;
    int s0, o0, C0, s1, o1, do_relu, sof, oof, sob, oob, rmode, M, K, nbc;
};

__global__ __launch_bounds__(256) void mfma_dense(GD A, GD B, int n0)
{
    // 48KB: A-buf b at [b*4096], B-buf b at [12288 + b*4096] (shorts)
    __shared__ __align__(16) unsigned short SM[24576];

    const int tid = threadIdx.x;
    const bool fa = (int)blockIdx.x < n0;

    const unsigned short* src0b = fa ? A.src0b : B.src0b;
    const unsigned short* src1b = fa ? A.src1b : B.src1b;
    const unsigned short* Wt    = fa ? A.Wt    : B.Wt;
    const float* bias           = fa ? A.bias  : B.bias;
    const int*   ridx0          = fa ? A.ridx0 : B.ridx0;
    float* outf                 = fa ? A.outf  : B.outf;
    unsigned short* outb        = fa ? A.outb  : B.outb;
    const int s0  = fa ? A.s0  : B.s0,  o0  = fa ? A.o0  : B.o0;
    const int C0  = fa ? A.C0  : B.C0;
    const int s1  = fa ? A.s1  : B.s1,  o1  = fa ? A.o1  : B.o1;
    const int do_relu = fa ? A.do_relu : B.do_relu;
    const int sof = fa ? A.sof : B.sof, oof = fa ? A.oof : B.oof;
    const int sob = fa ? A.sob : B.sob, oob = fa ? A.oob : B.oob;
    const int rmode = fa ? A.rmode : B.rmode;
    const int M   = fa ? A.M   : B.M;
    const int K   = fa ? A.K   : B.K;
    const int nbc = fa ? A.nbc : B.nbc;

    // bijective XCD swizzle within this descriptor's sub-grid
    const int nwg = fa ? n0 : (int)gridDim.x - n0;
    const int lb  = (int)blockIdx.x - (fa ? 0 : n0);
    const int q8  = nwg >> 3, r8 = nwg & 7;
    const int xcd = lb & 7, boff = lb >> 3;
    const int bid = (xcd < r8 ? xcd * (q8 + 1)
                              : r8 * (q8 + 1) + (xcd - r8) * q8) + boff;

    const int rb   = bid / nbc, cb = bid % nbc;
    const int r0   = rb * 128, c0 = cb * 128;
    const int wave = tid >> 6, lane = tid & 63;
    const int quad = lane >> 4, l16 = lane & 15;
    const int wm   = (wave & 1) * 64, wn = (wave >> 1) * 64;

    // staging slot geometry: slot g = i*256 + tid covers LDS bytes [g*16, g*16+16)
    // row = g>>2 (64B rows), k-chunk = (g&3)*8 bf16
    int arow[2], grow[2], brow[2], kch[2];
    #pragma unroll
    for (int i = 0; i < 2; ++i) {
        const int g  = i * 256 + tid;
        const int rr = g >> 2;
        kch[i] = (g & 3) << 3;
        int gr2 = r0 + rr;
        if (gr2 >= M) gr2 = M - 1;
        grow[i] = gr2;
        arow[i] = ridx0 ? ridx0[gr2] : gr2;
        brow[i] = c0 + rr;
    }

    floatx4 acc[4][4];
    #pragma unroll
    for (int i = 0; i < 4; ++i)
        #pragma unroll
        for (int j = 0; j < 4; ++j) acc[i][j] = (floatx4){0.f, 0.f, 0.f, 0.f};

    auto stage_tile = [&](int ts) {
        const int kk = ts << 5;
        const unsigned short *a0, *a1;
        if (kk < C0) {
            a0 = src0b + (long)arow[0] * s0 + o0 + kk + kch[0];
            a1 = src0b + (long)arow[1] * s0 + o0 + kk + kch[1];
        } else {
            a0 = src1b + (long)grow[0] * s1 + o1 + (kk - C0) + kch[0];
            a1 = src1b + (long)grow[1] * s1 + o1 + (kk - C0) + kch[1];
        }
        const unsigned short* b0 = Wt + (long)brow[0] * K + kk + kch[0];
        const unsigned short* b1 = Wt + (long)brow[1] * K + kk + kch[1];
        const int buf = ts % 3;
        glds16(a0, &SM[buf * 4096 + wave * 512]);
        glds16(b0, &SM[12288 + buf * 4096 + wave * 512]);
        glds16(a1, &SM[buf * 4096 + wave * 512 + 2048]);
        glds16(b1, &SM[12288 + buf * 4096 + wave * 512 + 2048]);
    };

    const int NT = K >> 5;
    stage_tile(0);
    if (NT > 1) stage_tile(1);

    for (int t = 0; t < NT; ++t) {
        // barrier: tile-t data ready everywhere; tile-(t+1) loads stay in flight
        if (t + 1 < NT)
            asm volatile("s_waitcnt vmcnt(4)" ::: "memory");
        else
            asm volatile("s_waitcnt vmcnt(0)" ::: "memory");
        __builtin_amdgcn_s_barrier();
        __builtin_amdgcn_sched_barrier(0);

        // issue next-next tile into the third buffer (no reader/loader on it)
        if (t + 2 < NT) stage_tile(t + 2);

        const int buf = t % 3;
        short8 af[4], bfr[4];
        #pragma unroll
        for (int mt = 0; mt < 4; ++mt)
            af[mt] = *(const short8*)(
                &SM[buf * 4096 + (wm + mt * 16 + l16) * 32 + quad * 8]);
        #pragma unroll
        for (int nt = 0; nt < 4; ++nt)
            bfr[nt] = *(const short8*)(
                &SM[12288 + buf * 4096 + (wn + nt * 16 + l16) * 32 + quad * 8]);
        __builtin_amdgcn_s_setprio(1);
        #pragma unroll
        for (int mt = 0; mt < 4; ++mt)
            #pragma unroll
            for (int nt = 0; nt < 4; ++nt)
                acc[mt][nt] = __builtin_amdgcn_mfma_f32_16x16x32_bf16(
                    af[mt], bfr[nt], acc[mt][nt], 0, 0, 0);
        __builtin_amdgcn_s_setprio(0);
    }

    if (outf) {
        #pragma unroll
        for (int nt = 0; nt < 4; ++nt) {
            const int gc = c0 + wn + nt * 16 + l16;
            const float bv = bias ? bias[gc] : 0.f;
            #pragma unroll
            for (int mt = 0; mt < 4; ++mt) {
                #pragma unroll
                for (int reg = 0; reg < 4; ++reg) {
                    const int grr = r0 + wm + mt * 16 + quad * 4 + reg;
                    if (grr < M) {
                        float v = acc[mt][nt][reg] + bv;
                        if (do_relu) v = fmaxf(v, 0.f);
                        outf[(long)grr * sof + oof + gc] = v;
                    }
                }
            }
        }
    }
    if (outb) {
        // bf16 path: LDS-staged coalesced epilogue, 2 passes of 64 rows.
        unsigned short* Cs = &SM[0];       // 64*128 shorts, fits in buf region
        __syncthreads();                   // all K-loop LDS traffic retired
        #pragma unroll
        for (int p = 0; p < 2; ++p) {
            if (wm == p * 64) {
                #pragma unroll
                for (int nt = 0; nt < 4; ++nt) {
                    const int col = wn + nt * 16 + l16;
                    const float bv = bias ? bias[c0 + col] : 0.f;
                    #pragma unroll
                    for (int mt = 0; mt < 4; ++mt) {
                        #pragma unroll
                        for (int reg = 0; reg < 4; ++reg) {
                            float v = acc[mt][nt][reg] + bv;
                            if (do_relu) v = fmaxf(v, 0.f);
                            Cs[(mt * 16 + quad * 4 + reg) * 128 + col] = f2bf(v);
                        }
                    }
                }
            }
            __syncthreads();
            const int rl  = tid >> 2;
            const int cc0 = (tid & 3) << 3;
            const int grr2 = r0 + p * 64 + rl;
            if (grr2 < M) {
                const long rowbase = (rmode == 2)
                    ? ((long)(c0 >> 8) * ((long)N_EDGES * 256)
                       + (long)grr2 * 256 + (c0 & 255))
                    : ((long)grr2 * sob + oob + c0);
                #pragma unroll
                for (int j = 0; j < 4; ++j)
                    *(ushort8*)(outb + rowbase + cc0 + j * 32) =
                        *(const ushort8*)(&Cs[rl * 128 + cc0 + j * 32]);
            }
            __syncthreads();
        }
    }
}

// ---------------------------------------------------------------------------
// Aggregation: one wave per dst node, TWO edges in flight (named slots A/B).
// Summation order identical to serial loop -> bitwise-identical results.
// ---------------------------------------------------------------------------
__global__ __launch_bounds__(256) void agg_kernel(
    const unsigned short* __restrict__ pq,
    const int* __restrict__ rowptr,
    const int* __restrict__ ssrc,
    const float* __restrict__ sew,
    const unsigned short* __restrict__ Rb,
    const float* __restrict__ resid,
    const float* __restrict__ bias,
    float* __restrict__ out, int fofs, int rofs,
    unsigned short* __restrict__ nfbf, int nofs)
{
    const int wid  = (blockIdx.x * blockDim.x + threadIdx.x) >> 6;
    const int lane = threadIdx.x & 63;
    if (wid >= N_NODES) return;
    const int c = lane * 4;

    const ushort4v p4 = *(const ushort4v*)(pq + (long)wid * 512 + c);
    const float4 bb = *(const float4*)(bias + c);
    float pb[4] = {bf2f(p4[0]) + bb.x, bf2f(p4[1]) + bb.y,
                   bf2f(p4[2]) + bb.z, bf2f(p4[3]) + bb.w};
    float acc[4] = {0.f, 0.f, 0.f, 0.f};

    int s = rowptr[wid];
    const int sEnd = rowptr[wid + 1];

    ushort4v qA, rA, qB, rB;
    float wA = 0.f, wB = 0.f;
    if (s < sEnd) {
        const int n_ = ssrc[s];
        wA = sew[s];
        qA = *(const ushort4v*)(pq + (long)n_ * 512 + 256 + c);
        rA = *(const ushort4v*)(Rb + (long)s * 256 + c);
    }
    if (s + 1 < sEnd) {
        const int n_ = ssrc[s + 1];
        wB = sew[s + 1];
        qB = *(const ushort4v*)(pq + (long)n_ * 512 + 256 + c);
        rB = *(const ushort4v*)(Rb + (long)(s + 1) * 256 + c);
    }
    while (s + 1 < sEnd) {
        #pragma unroll
        for (int j = 0; j < 4; ++j)
            acc[j] += fmaxf(pb[j] + bf2f(qA[j]) + bf2f(rA[j]), 0.f) * wA;
        if (s + 2 < sEnd) {
            const int n_ = ssrc[s + 2];
            wA = sew[s + 2];
            qA = *(const ushort4v*)(pq + (long)n_ * 512 + 256 + c);
            rA = *(const ushort4v*)(Rb + (long)(s + 2) * 256 + c);
        }
        #pragma unroll
        for (int j = 0; j < 4; ++j)
            acc[j] += fmaxf(pb[j] + bf2f(qB[j]) + bf2f(rB[j]), 0.f) * wB;
        if (s + 3 < sEnd) {
            const int n_ = ssrc[s + 3];
            wB = sew[s + 3];
            qB = *(const ushort4v*)(pq + (long)n_ * 512 + 256 + c);
            rB = *(const ushort4v*)(Rb + (long)(s + 3) * 256 + c);
        }
        s += 2;
    }
    if (s < sEnd) {
        #pragma unroll
        for (int j = 0; j < 4; ++j)
            acc[j] += fmaxf(pb[j] + bf2f(qA[j]) + bf2f(rA[j]), 0.f) * wA;
    }
    if (rofs >= 0) {
        const float4 f4 = *(const float4*)(resid + (long)wid * OUT_STRIDE + rofs + c);
        acc[0] += f4.x; acc[1] += f4.y; acc[2] += f4.z; acc[3] += f4.w;
    }
    float4 o; o.x = acc[0]; o.y = acc[1]; o.z = acc[2]; o.w = acc[3];
    *(float4*)(out + (long)wid * OUT_STRIDE + fofs + c) = o;
    ushort4v hb = (ushort4v){f2bf(acc[0]), f2bf(acc[1]), f2bf(acc[2]), f2bf(acc[3])};
    *(ushort4v*)(nfbf + (long)wid * FD + nofs + c) = hb;
}

// ---------------------------------------------------------------------------
// Mega prep kernel: zeroing + both f32->bf16 converts + all weight preps in
// ONE launch. Flat region decode on blockIdx.x.
// ---------------------------------------------------------------------------
__device__ __forceinline__ void tr_block(const float* inp, unsigned short* outp,
                                         int K, int N, int bidx, int tid,
                                         float (*tile)[33])
{
    const int nbx = N >> 5;
    const int n0 = (bidx % nbx) << 5;
    const int k0 = (bidx / nbx) << 5;
    const int tx = tid & 31, ty = tid >> 5;
    #pragma unroll
    for (int r = 0; r < 4; ++r)
        tile[ty + r * 8][tx] = inp[(long)(k0 + ty + r * 8) * N + n0 + tx];
    __syncthreads();
    #pragma unroll
    for (int r = 0; r < 4; ++r)
        outp[(long)(n0 + ty + r * 8) * K + k0 + tx] = f2bf(tile[tx][ty + r * 8]);
}

#define PB_ZERO  79     // (20001 + 129 + 255)/256
#define PB_CVTX  1250
#define PB_CVTE  3125
#define PB_WPQ0  128
#define PB_WPQ3  384
#define PB_WTR   128
#define PB_TS0   80
#define PB_TS3   384
#define PB_TF    1024
#define PREP_BLOCKS (PB_ZERO+PB_CVTX+PB_CVTE+PB_WPQ0+PB_WPQ3+PB_WTR+PB_TS0+PB_TS3+PB_TF+PB_TF)

__global__ __launch_bounds__(256) void prep_all(
    const float* __restrict__ x, const float* __restrict__ ea,
    const float* __restrict__ W_msg0, const float* __restrict__ W_msg,
    const float* __restrict__ W_sup0, const float* __restrict__ W_sup,
    const float* __restrict__ W_fuse, const float* __restrict__ W_fsup,
    unsigned short* __restrict__ xb, unsigned short* __restrict__ eab,
    unsigned short* __restrict__ wpq0, unsigned short* __restrict__ wpq,
    unsigned short* __restrict__ wtr,
    unsigned short* __restrict__ wt_sup0, unsigned short* __restrict__ wt_sup,
    unsigned short* __restrict__ wt_fuse, unsigned short* __restrict__ wt_fsup,
    int* __restrict__ cnt, int* __restrict__ bcnt)
{
    __shared__ float tile[32][33];
    const int tid = threadIdx.x;
    int b = blockIdx.x;

    if (b < PB_ZERO) {                       // zero CSR counters
        int i = b * 256 + tid;
        if (i < N_NODES + 1) cnt[i] = 0;
        else if (i - (N_NODES + 1) < 129) bcnt[i - (N_NODES + 1)] = 0;
        return;
    }
    b -= PB_ZERO;
    if (b < PB_CVTX) {
        int i = b * 256 + tid;
        float4 v = ((const float4*)x)[i];
        ((ushort4v*)xb)[i] = (ushort4v){f2bf(v.x), f2bf(v.y), f2bf(v.z), f2bf(v.w)};
        return;
    }
    b -= PB_CVTX;
    if (b < PB_CVTE) {
        int i = b * 256 + tid;
        float4 v = ((const float4*)ea)[i];
        ((ushort4v*)eab)[i] = (ushort4v){f2bf(v.x), f2bf(v.y), f2bf(v.z), f2bf(v.w)};
        return;
    }
    b -= PB_CVTE;
    if (b < PB_WPQ0) {
        int i = b * 256 + tid;
        int nn = i >> 6, k = i & 63;
        float v = (nn < 256) ? (W_msg0[k * 256 + nn] - W_msg0[(64 + k) * 256 + nn])
                             : (W_msg0[(64 + k) * 256 + (nn - 256)]);
        wpq0[(long)nn * 64 + k] = f2bf(v);
        return;
    }
    b -= PB_WPQ0;
    if (b < PB_WPQ3) {
        const int slab = b / 128, bb = b % 128;
        const float* Wi = W_msg + (long)slab * 544 * 256;
        unsigned short* Wo = wpq + (long)slab * 512 * 256;
        const int n0 = (bb & 15) << 5;
        const int k0 = (bb >> 4) << 5;
        const int tx = tid & 31, ty = tid >> 5;
        #pragma unroll
        for (int r = 0; r < 4; ++r) {
            const int k = k0 + ty + r * 8;
            float v;
            if (n0 < 256)
                v = Wi[(long)k * 256 + n0 + tx] - Wi[(long)(256 + k) * 256 + n0 + tx];
            else
                v = Wi[(long)(256 + k) * 256 + (n0 - 256) + tx];
            tile[ty + r * 8][tx] = v;
        }
        __syncthreads();
        #pragma unroll
        for (int r = 0; r < 4; ++r)
            Wo[(long)(n0 + ty + r * 8) * 256 + k0 + tx] = f2bf(tile[tx][ty + r * 8]);
        return;
    }
    b -= PB_WPQ3;
    if (b < PB_WTR) {
        const int j = b >> 5;
        const float* Wi = (j == 0) ? (W_msg0 + 2 * CIN * 256)
                                   : (W_msg + (long)(j - 1) * 544 * 256 + 2 * CCH * 256);
        unsigned short* Wo = wtr + (long)j * 256 * 32;
        int i = (b & 31) * 256 + tid;
        int k = i >> 8, n = i & 255;
        Wo[(long)n * 32 + k] = f2bf(Wi[i]);
        return;
    }
    b -= PB_WTR;
    if (b < PB_TS0) { tr_block(W_sup0, wt_sup0, 320, 256, b, tid, tile); return; }
    b -= PB_TS0;
    if (b < PB_TS3) {
        const int slab = b / 128;
        tr_block(W_sup + (long)slab * 512 * 256, wt_sup + (long)slab * 256 * 512,
                 512, 256, b % 128, tid, tile);
        return;
    }
    b -= PB_TS3;
    if (b < PB_TF) { tr_block(W_fuse, wt_fuse, 1024, 1024, b, tid, tile); return; }
    b -= PB_TF;
    tr_block(W_fsup, wt_fsup, 1024, 1024, b, tid, tile);
}

// ---------------------------------------------------------------------------
// CSR build (edge + box variants merged per stage)
// ---------------------------------------------------------------------------
__global__ void hist2(const int* __restrict__ dst, const int* __restrict__ bbox,
                      int* __restrict__ cnt, int* __restrict__ bcnt) {
    int i = blockIdx.x * blockDim.x + threadIdx.x;
    if (i < N_EDGES) atomicAdd(&cnt[dst[i]], 1);
    else if (i - N_EDGES < N_NODES) atomicAdd(&bcnt[bbox[i - N_EDGES]], 1);
}
__global__ __launch_bounds__(1024) void scan2(
    const int* __restrict__ cnt,  int* __restrict__ rowptr, int* __restrict__ ofs,
    const int* __restrict__ bcnt, int* __restrict__ bptr,   int* __restrict__ bofs)
{
    __shared__ int part[1024];
    const int tid = threadIdx.x;
    const int n = blockIdx.x == 0 ? N_NODES : NBOX;
    const int* c   = blockIdx.x == 0 ? cnt    : bcnt;
    int* rp        = blockIdx.x == 0 ? rowptr : bptr;
    int* op        = blockIdx.x == 0 ? ofs    : bofs;
    const int chunk = (n + 1023) >> 10;
    int s = 0;
    for (int j = 0; j < chunk; ++j) {
        int i = tid * chunk + j;
        if (i < n) s += c[i];
    }
    part[tid] = s; __syncthreads();
    for (int d = 1; d < 1024; d <<= 1) {
        int v = (tid >= d) ? part[tid - d] : 0;
        __syncthreads();
        part[tid] += v;
        __syncthreads();
    }
    int run = (tid > 0) ? part[tid - 1] : 0;
    for (int j = 0; j < chunk; ++j) {
        int i = tid * chunk + j;
        if (i < n) { rp[i] = run; op[i] = run; run += c[i]; }
    }
    if (tid == 1023) rp[n] = part[1023];
}
__global__ void scatter2(const int* __restrict__ src, const int* __restrict__ dst,
                         const float* __restrict__ ew, int* __restrict__ ofs,
                         int* __restrict__ ssrc, float* __restrict__ sew,
                         int* __restrict__ seid,
                         const int* __restrict__ bbox, int* __restrict__ bofs,
                         int* __restrict__ snode) {
    int i = blockIdx.x * blockDim.x + threadIdx.x;
    if (i < N_EDGES) {
        int pos = atomicAdd(&ofs[dst[i]], 1);
        ssrc[pos] = src[i];
        sew[pos]  = ew[i];
        seid[pos] = i;
    } else if (i - N_EDGES < N_NODES) {
        int j = i - N_EDGES;
        int pos = atomicAdd(&bofs[bbox[j]], 1);
        snode[pos] = j;
    }
}

// ---------------------------------------------------------------------------
// Box mean via CSR, 1-deep gather prefetch. Emits fp32 + bf16 fsmean.
// ---------------------------------------------------------------------------
__global__ __launch_bounds__(256) void box_mean_csr(
    const unsigned short* __restrict__ fsbf, const int* __restrict__ bptr,
    const int* __restrict__ snode, float* __restrict__ out_super,
    unsigned short* __restrict__ fsmeanb)
{
    const int b = blockIdx.x >> 2;
    const int c = ((blockIdx.x & 3) << 8) + threadIdx.x;
    const int s0 = bptr[b], s1 = bptr[b + 1];
    float sum = 0.f;
    int s = s0;
    unsigned short hn = 0;
    if (s < s1) hn = fsbf[(long)snode[s] * FD + c];
    while (s < s1) {
        const unsigned short h = hn;
        if (s + 1 < s1) hn = fsbf[(long)snode[s + 1] * FD + c];
        sum += bf2f(h);
        ++s;
    }
    const float mean = sum / fmaxf((float)(s1 - s0), 1.f);
    out_super[(long)b * OUT_STRIDE + HID + c] = mean;
    fsmeanb[(long)b * FD + c] = f2bf(mean);
}

// ---------------------------------------------------------------------------
extern "C" void kernel_launch(void* const* d_in, const int* in_sizes, int n_in,
                              void* d_out, int out_size, void* d_ws, size_t ws_size,
                              hipStream_t stream) {
    const float* x      = (const float*)d_in[0];
    const int*   edges  = (const int*)d_in[1];
    const float* ew     = (const float*)d_in[2];
    const float* ea     = (const float*)d_in[3];
    const int*   bbox   = (const int*)d_in[4];
    const float* W_msg0 = (const float*)d_in[6];
    const float* b_msg0 = (const float*)d_in[7];
    const float* W_sup0 = (const float*)d_in[8];
    const float* b_sup0 = (const float*)d_in[9];
    const float* W_msg  = (const float*)d_in[10];
    const float* b_msg  = (const float*)d_in[11];
    const float* W_sup  = (const float*)d_in[12];
    const float* b_sup  = (const float*)d_in[13];
    const float* W_fuse = (const float*)d_in[14];
    const float* b_fuse = (const float*)d_in[15];
    const float* W_fsup = (const float*)d_in[16];
    const float* b_fsup = (const float*)d_in[17];

    float* out       = (float*)d_out;
    float* out_super = out + (long)N_NODES * OUT_STRIDE;

    // ---- workspace layout ----
    char* w = (char*)d_ws;
    auto alloc = [&](size_t bytes) { char* p = w; w += (bytes + 63) & ~63ULL; return p; };
    unsigned short* fsbf    = (unsigned short*)alloc((size_t)N_NODES * FD * 2);
    unsigned short* nfbf    = (unsigned short*)alloc((size_t)N_NODES * FD * 2);
    unsigned short* pq      = (unsigned short*)alloc((size_t)N_NODES * 512 * 2);
    unsigned short* xb      = (unsigned short*)alloc((size_t)N_NODES * CIN * 2);
    unsigned short* eab     = (unsigned short*)alloc((size_t)N_EDGES * A_DIM * 2);
    unsigned short* Rb4     = (unsigned short*)alloc((size_t)N_EDGES * 1024 * 2);
    unsigned short* wpq0    = (unsigned short*)alloc((size_t)512 * CIN * 2);
    unsigned short* wpq     = (unsigned short*)alloc((size_t)3 * 512 * CCH * 2);
    unsigned short* wtr     = (unsigned short*)alloc((size_t)4 * 256 * 32 * 2);
    unsigned short* wt_sup0 = (unsigned short*)alloc((size_t)256 * 320 * 2);
    unsigned short* wt_sup  = (unsigned short*)alloc((size_t)3 * 256 * 512 * 2);
    unsigned short* wt_fuse = (unsigned short*)alloc((size_t)1024 * 1024 * 2);
    unsigned short* wt_fsup = (unsigned short*)alloc((size_t)1024 * 1024 * 2);
    unsigned short* fsmeanb = (unsigned short*)alloc((size_t)NBOX * FD * 2);
    float* sew        = (float*)alloc((size_t)N_EDGES * 4);
    int* cnt          = (int*)alloc((size_t)(N_NODES + 1) * 4);
    int* rowptr       = (int*)alloc((size_t)(N_NODES + 1) * 4);
    int* ofs          = (int*)alloc((size_t)(N_NODES + 1) * 4);
    int* ssrc         = (int*)alloc((size_t)N_EDGES * 4);
    int* seid         = (int*)alloc((size_t)N_EDGES * 4);
    int* bcnt         = (int*)alloc(129 * 4);
    int* bptr         = (int*)alloc(129 * 4);
    int* bofs         = (int*)alloc(129 * 4);
    int* snode        = (int*)alloc((size_t)N_NODES * 4);

    const int* srcp = edges;
    const int* dstp = edges + N_EDGES;

    // ---- prep + CSR-zero (1 launch) ----
    prep_all<<<PREP_BLOCKS, 256, 0, stream>>>(
        x, ea, W_msg0, W_msg, W_sup0, W_sup, W_fuse, W_fsup,
        xb, eab, wpq0, wpq, wtr, wt_sup0, wt_sup, wt_fuse, wt_fsup,
        cnt, bcnt);

    // ---- CSR build (3 launches) ----
    hist2<<<(N_EDGES + N_NODES + 255) / 256, 256, 0, stream>>>(dstp, bbox, cnt, bcnt);
    scan2<<<2, 1024, 0, stream>>>(cnt, rowptr, ofs, bcnt, bptr, bofs);
    scatter2<<<(N_EDGES + N_NODES + 255) / 256, 256, 0, stream>>>(
        srcp, dstp, ew, ofs, ssrc, sew, seid, bbox, bofs, snode);

    const int GRB = (N_NODES + 127) / 128;   // 157
    const int GEB = (N_EDGES + 127) / 128;   // 782
    const long RLS = (long)N_EDGES * 256;    // R layer stride (shorts)

    auto mk = [](const unsigned short* src0b, int s0, int o0, int C0,
                 const int* ridx0,
                 const unsigned short* src1b, int s1, int o1,
                 const unsigned short* Wt, const float* bias, int relu,
                 float* outf, int sof, int oof,
                 unsigned short* outb, int sob, int oob, int rmode,
                 int M, int K, int nbc) {
        GD g;
        g.src0b = src0b; g.s0 = s0; g.o0 = o0; g.C0 = C0;
        g.ridx0 = ridx0;
        g.src1b = src1b; g.s1 = s1; g.o1 = o1;
        g.Wt = Wt; g.bias = bias; g.do_relu = relu;
        g.outf = outf; g.sof = sof; g.oof = oof;
        g.outb = outb; g.sob = sob; g.oob = oob; g.rmode = rmode;
        g.M = M; g.K = K; g.nbc = nbc;
        return g;
    };

    GD gR   = mk(eab, A_DIM, 0, A_DIM, seid, nullptr, 0, 0, wtr, nullptr, 0,
                 nullptr, 0, 0, Rb4, 0, 0, 2, N_EDGES, A_DIM, 8);
    GD gPQh = mk(xb, CIN, 0, CIN, nullptr, nullptr, 0, 0, wpq0, nullptr, 0,
                 nullptr, 0, 0, pq, 512, 0, 0, N_NODES, CIN, 4);
    GD gS0  = mk(nfbf, FD, 0, CCH, nullptr, xb, CIN, 0, wt_sup0, b_sup0, 1,
                 nullptr, 0, 0, fsbf, FD, 0, 0, N_NODES, CCH + CIN, 2);
    GD gPQ[3], gS[3];
    for (int i = 0; i < 3; ++i) {
        gPQ[i] = mk(nfbf, FD, CCH * i, CCH, nullptr, nullptr, 0, 0,
                    wpq + (long)i * 512 * CCH, nullptr, 0,
                    nullptr, 0, 0, pq, 512, 0, 0, N_NODES, CCH, 4);
        gS[i]  = mk(nfbf, FD, CCH * (i + 1), CCH, nullptr, fsbf, FD, CCH * i,
                    wt_sup + (long)i * 256 * 512, b_sup + i * CCH, 1,
                    nullptr, 0, 0, fsbf, FD, CCH * (i + 1), 0, N_NODES, 2 * CCH, 2);
    }
    GD gFU  = mk(nfbf, FD, 0, FD, nullptr, nullptr, 0, 0, wt_fuse, b_fuse, 1,
                 out, OUT_STRIDE, 0, nullptr, 0, 0, 0, N_NODES, FD, 8);
    GD gFS  = mk(fsmeanb, FD, 0, FD, nullptr, nullptr, 0, 0, wt_fsup, b_fsup, 1,
                 out_super, OUT_STRIDE, 0, nullptr, 0, 0, 0, NBOX, FD, 8);

    const int AGRID = (N_NODES + 3) / 4;

    // ---- R GEMM (all 4 layers) || head pq GEMM ----
    mfma_dense<<<GEB * 8 + GRB * 4, 256, 0, stream>>>(gR, gPQh, GEB * 8);

    // ---- head agg ----
    agg_kernel<<<AGRID, 256, 0, stream>>>(pq, rowptr, ssrc, sew,
        Rb4, out, b_msg0, out, HID, -1, nfbf, 0);

    // ---- [sup_head || pq_res0] -> agg_res0 -> [sup_res0 || pq_res1] -> ... ----
    mfma_dense<<<GRB * 6, 256, 0, stream>>>(gS0, gPQ[0], GRB * 2);
    for (int i = 0; i < 3; ++i) {
        agg_kernel<<<AGRID, 256, 0, stream>>>(pq, rowptr, ssrc, sew,
            Rb4 + (long)(i + 1) * RLS, out, b_msg + i * CCH,
            out, HID + CCH * (i + 1), HID + CCH * i, nfbf, CCH * (i + 1));
        if (i < 2)
            mfma_dense<<<GRB * 6, 256, 0, stream>>>(gS[i], gPQ[i + 1], GRB * 2);
    }

    // ---- [sup_res2 || fusion] ----
    mfma_dense<<<GRB * 10, 256, 0, stream>>>(gS[2], gFU, GRB * 2);

    // ---- super path ----
    box_mean_csr<<<NBOX * 4, 256, 0, stream>>>(fsbf, bptr, snode, out_super, fsmeanb);
    mfma_dense<<<8, 256, 0, stream>>>(gFS, gFS, 8);
}